// Round 14
// baseline (815.147 us; speedup 1.0000x reference)
//
#include <hip/hip_runtime.h>
#include <cstdint>
#include <cstddef>

// ---------------------------------------------------------------------------
// DeeperGCN forward on MI355X. Round 14: 1024-thread layer blocks (16 waves),
// 1 node/wave aggregation with quarter-wave uint4 gathers (4 edges per
// instruction x 4 chains = 16 edges in flight; iterations = ceil(deg/16),
// no pair-max penalty). gemm1 over 16 waves; gemm2 on waves 0-7 (all waves
// share barriers). 16-row tiles, 625 blocks.
// N=10000 nodes, E=160000 edges, H=128, L=14 layers, G=64 graphs.
// ---------------------------------------------------------------------------

typedef __attribute__((ext_vector_type(8))) short bf16x8;
typedef __attribute__((ext_vector_type(4))) float f32x4;

__device__ inline float bf2f(ushort u) {
    union { uint i; float f; } v;
    v.i = (uint)u << 16;
    return v.f;
}
__device__ inline ushort f2bf(float f) {
    union { float f; uint i; } v;
    v.f = f;
    return (ushort)((v.i + 0x7fffu + ((v.i >> 16) & 1u)) >> 16);
}
__device__ inline uint f2bf2(float a, float b) {
    return (uint)f2bf(a) | ((uint)f2bf(b) << 16);
}

// ---------------- setup: xb convert + deg histogram + graph boundaries -----
__global__ void setup_kernel(const float* __restrict__ x, ushort* __restrict__ xb,
                             const int* __restrict__ dst, int* __restrict__ deg,
                             const int* __restrict__ batch, int* __restrict__ gstart,
                             int total, int N, int E, int G) {
    int idx = blockIdx.x * blockDim.x + threadIdx.x;
    if (idx >= total) return;
    xb[idx] = f2bf(x[idx]);
    if (idx < E) atomicAdd(&deg[dst[idx]], 1);
    if (idx < N) {
        int bb = batch[idx];
        if (idx == 0)
            for (int g = 0; g <= bb; g++) gstart[g] = 0;
        else {
            int pb = batch[idx - 1];
            for (int g = pb + 1; g <= bb; g++) gstart[g] = idx;
        }
        if (idx == N - 1)
            for (int g = bb + 1; g <= G; g++) gstart[g] = N;
    }
}

// single-workgroup exclusive scan of deg -> offs, cursor
__global__ __launch_bounds__(1024) void scan_kernel(const int* __restrict__ deg,
                                                    int* __restrict__ offs,
                                                    int* __restrict__ cursor, int N) {
    __shared__ int part[1024];
    int tid = threadIdx.x;
    int CH = (N + 1023) / 1024;
    int base = tid * CH;
    int s = 0;
    for (int i = 0; i < CH; i++) {
        int idx = base + i;
        if (idx < N) s += deg[idx];
    }
    part[tid] = s;
    __syncthreads();
    for (int off = 1; off < 1024; off <<= 1) {
        int v = (tid >= off) ? part[tid - off] : 0;
        __syncthreads();
        part[tid] += v;
        __syncthreads();
    }
    int run = (tid == 0) ? 0 : part[tid - 1];
    for (int i = 0; i < CH; i++) {
        int idx = base + i;
        if (idx < N) {
            offs[idx] = run;
            cursor[idx] = run;
            run += deg[idx];
        }
    }
    if (tid == 1023) offs[N] = part[1023];
}

__global__ void scatter_kernel(const int* __restrict__ src, const int* __restrict__ dst,
                               int* __restrict__ cursor, int* __restrict__ esrc, int E) {
    int e = blockIdx.x * blockDim.x + threadIdx.x;
    if (e < E) {
        int d = dst[e];
        int pos = atomicAdd(&cursor[d], 1);
        esrc[pos] = src[e];
    }
}

// ---------------- weight prep: fp32 [R][C] -> bf16 [C][R], all matrices ----
__global__ __launch_bounds__(256) void prep_kernel(const float* __restrict__ W1,
                                                   const float* __restrict__ W2,
                                                   const float* __restrict__ encW,
                                                   ushort* __restrict__ W1t,
                                                   ushort* __restrict__ W2t,
                                                   ushort* __restrict__ encWt, int L) {
    __shared__ float tile[32][33];
    int z = blockIdx.z;
    const float* in;
    ushort* out;
    int R, C;
    if (z < L) {
        in = W1 + (size_t)z * 32768; out = W1t + (size_t)z * 32768; R = 128; C = 256;
    } else if (z < 2 * L) {
        int i = z - L;
        in = W2 + (size_t)i * 32768; out = W2t + (size_t)i * 32768; R = 256; C = 128;
    } else {
        in = encW; out = encWt; R = 128; C = 128;
    }
    int r0 = blockIdx.y * 32, c0 = blockIdx.x * 32;
    if (r0 >= R || c0 >= C) return;
    int tx = threadIdx.x & 31, ty = threadIdx.x >> 5;
    for (int i = ty; i < 32; i += 8) tile[i][tx] = in[(size_t)(r0 + i) * C + c0 + tx];
    __syncthreads();
    for (int i = ty; i < 32; i += 8)
        out[(size_t)(c0 + i) * R + r0 + tx] = f2bf(tile[tx][i]);
}

// ---- agg v14: 1 node/wave, quarter-wave uint4 gathers, 4 chains ------------
// Max-free softmax (z=(relu+eps)*t bounded -> fp32 exp safe), associative.
__device__ __forceinline__ void agg_stage_v14(const ushort* __restrict__ rin,
                                              const int* __restrict__ offs,
                                              const int* __restrict__ esrc,
                                              const float* __restrict__ rnbuf,
                                              float tv, float sv, int row0,
                                              int w, int l, ushort (*As)[136]) {
    const uint4* rin4 = (const uint4*)rin;
    int nd = row0 + w;
    int qt = l >> 4, qi = l & 15;
    int e0 = offs[nd];
    int deg = offs[nd + 1] - e0;
    float s[8] = {}, W[8] = {};
#pragma unroll 1
    for (int base = 0; base < deg; base += 64) {
        int rem = min(deg - base, 64);
        int idx = (l < rem) ? esrc[e0 + base + l] : 0;
        int it = (rem + 15) >> 4;
#pragma unroll 1
        for (int i = 0; i < it; i++) {
            uint4 rv[4];
            bool vl[4];
#pragma unroll
            for (int c = 0; c < 4; c++) {
                int j = i * 16 + qt + 4 * c;
                vl[c] = j < rem;
                int sn = __shfl(idx, j, 64);
                if (vl[c]) rv[c] = rin4[(size_t)sn * 16 + qi];
            }
#pragma unroll
            for (int c = 0; c < 4; c++) {
                if (vl[c]) {
                    uint px[4] = {rv[c].x, rv[c].y, rv[c].z, rv[c].w};
#pragma unroll
                    for (int h2 = 0; h2 < 4; h2++) {
                        float x0 = bf2f((ushort)(px[h2] & 0xffff));
                        float x1 = bf2f((ushort)(px[h2] >> 16));
                        float g0 = fmaxf(x0, 0.f) + 1e-7f;
                        float g1 = fmaxf(x1, 0.f) + 1e-7f;
                        float p0 = __expf(g0 * tv);
                        float p1 = __expf(g1 * tv);
                        s[2 * h2] += p0;
                        W[2 * h2] += g0 * p0;
                        s[2 * h2 + 1] += p1;
                        W[2 * h2 + 1] += g1 * p1;
                    }
                }
            }
        }
    }
    // merge 4 quarters (lanes differ in bits 4-5)
#pragma unroll
    for (int f = 0; f < 8; f++) {
        s[f] += __shfl_xor(s[f], 16, 64);
        s[f] += __shfl_xor(s[f], 32, 64);
        W[f] += __shfl_xor(W[f], 16, 64);
        W[f] += __shfl_xor(W[f], 32, 64);
    }
    float agg[8], nsq = 0.f;
#pragma unroll
    for (int f = 0; f < 8; f++) {
        agg[f] = W[f] / (s[f] + 1e-16f);
        nsq += agg[f] * agg[f];
    }
#pragma unroll
    for (int off = 1; off < 16; off <<= 1) nsq += __shfl_xor(nsq, off, 64);
    float fac = rnbuf[nd] * sv / fmaxf(sqrtf(nsq), 1e-12f);
    uint4 ru = rin4[(size_t)nd * 16 + qi];
    if (qt == 0) {
        uint px[4] = {ru.x, ru.y, ru.z, ru.w};
        uint o[4];
#pragma unroll
        for (int h2 = 0; h2 < 4; h2++) {
            float x0 = bf2f((ushort)(px[h2] & 0xffff)) + agg[2 * h2] * fac;
            float x1 = bf2f((ushort)(px[h2] >> 16)) + agg[2 * h2 + 1] * fac;
            o[h2] = f2bf2(x0, x1);
        }
        uint4 ov = make_uint4(o[0], o[1], o[2], o[3]);
        *(uint4*)&As[w][qi * 8] = ov;  // row stride 272B = 17*16 -> 16B aligned
    }
}

// ---------------- fused layer: 1024 thr, agg + gemm1(16w) + gemm2(8w) ------
__global__ __launch_bounds__(1024) void layer_kernel(const ushort* __restrict__ rin,
                                                     ushort* __restrict__ rout,
                                                     const int* __restrict__ offs,
                                                     const int* __restrict__ esrc,
                                                     float* __restrict__ rn,
                                                     float* __restrict__ h,
                                                     const ushort* __restrict__ W1t,
                                                     const ushort* __restrict__ W2t,
                                                     const float* __restrict__ b1,
                                                     const float* __restrict__ mg,
                                                     const float* __restrict__ mb,
                                                     const float* __restrict__ b2,
                                                     const float* __restrict__ ng,
                                                     const float* __restrict__ nb,
                                                     const float* __restrict__ tptr,
                                                     const float* __restrict__ scptr,
                                                     int N) {
    __shared__ __align__(16) ushort As[16][136];
    __shared__ __align__(16) ushort z1s[16][264];
    __shared__ float pS[16][16], pQ[16][16];
    int tid = threadIdx.x, w = tid >> 6, l = tid & 63;
    int q = l >> 4, ln = l & 15;
    int row0 = blockIdx.x * 16;
    float tv = *tptr, sv = *scptr;

    agg_stage_v14(rin, offs, esrc, rn, tv, sv, row0, w, l, As);
    __syncthreads();

    // ---- gemm1: 16 waves x 16 cols = 256 cols; LN256 + relu -> z1s --------
    {
        int col = w * 16 + ln;
        f32x4 acc = (f32x4){0.f, 0.f, 0.f, 0.f};
#pragma unroll
        for (int ks = 0; ks < 128; ks += 32) {
            bf16x8 a = *(const bf16x8*)&As[ln][ks + q * 8];
            bf16x8 bv = *(const bf16x8*)(W1t + (size_t)col * 128 + ks + q * 8);
            acc = __builtin_amdgcn_mfma_f32_16x16x32_bf16(a, bv, acc, 0, 0, 0);
        }
        float s1[4], s2[4];
#pragma unroll
        for (int r = 0; r < 4; r++) {
            float v = acc[r] + b1[col];
            acc[r] = v;
            s1[r] = v;
            s2[r] = v * v;
        }
#pragma unroll
        for (int off = 1; off < 16; off <<= 1)
#pragma unroll
            for (int r = 0; r < 4; r++) {
                s1[r] += __shfl_xor(s1[r], off, 64);
                s2[r] += __shfl_xor(s2[r], off, 64);
            }
        if (ln == 0)
#pragma unroll
            for (int r = 0; r < 4; r++) {
                pS[w][q * 4 + r] = s1[r];
                pQ[w][q * 4 + r] = s2[r];
            }
        __syncthreads();
#pragma unroll
        for (int r = 0; r < 4; r++) {
            int row = q * 4 + r;
            float S = 0.f, Q = 0.f;
#pragma unroll
            for (int ww = 0; ww < 16; ww++) {
                S += pS[ww][row];
                Q += pQ[ww][row];
            }
            float mu = S * (1.f / 256.f);
            float var = Q * (1.f / 256.f) - mu * mu;
            float rs = rsqrtf(var + 1e-5f);
            float y = (acc[r] - mu) * rs * mg[col] + mb[col];
            z1s[row][col] = f2bf(fmaxf(y, 0.f));
        }
    }
    __syncthreads();

    // ---- gemm2: waves 0-7 x 16 cols = 128 cols; resid + LN128 + lrelu -----
    f32x4 acc2 = (f32x4){0.f, 0.f, 0.f, 0.f};
    int col2 = (w & 7) * 16 + ln;
    if (w < 8) {
#pragma unroll
        for (int ks = 0; ks < 256; ks += 32) {
            bf16x8 a = *(const bf16x8*)&z1s[ln][ks + q * 8];
            bf16x8 bv = *(const bf16x8*)(W2t + (size_t)col2 * 256 + ks + q * 8);
            acc2 = __builtin_amdgcn_mfma_f32_16x16x32_bf16(a, bv, acc2, 0, 0, 0);
        }
        float s1[4], s2[4];
#pragma unroll
        for (int r = 0; r < 4; r++) {
            int row = q * 4 + r;
            float v = acc2[r] + b2[col2] + h[(size_t)(row0 + row) * 128 + col2];
            h[(size_t)(row0 + row) * 128 + col2] = v;
            acc2[r] = v;
            s1[r] = v;
            s2[r] = v * v;
        }
#pragma unroll
        for (int off = 1; off < 16; off <<= 1)
#pragma unroll
            for (int r = 0; r < 4; r++) {
                s1[r] += __shfl_xor(s1[r], off, 64);
                s2[r] += __shfl_xor(s2[r], off, 64);
            }
        if (ln == 0)
#pragma unroll
            for (int r = 0; r < 4; r++) {
                pS[w][q * 4 + r] = s1[r];
                pQ[w][q * 4 + r] = s2[r];
            }
    }
    __syncthreads();
    float yv[4], t2[4];
    if (w < 8) {
#pragma unroll
        for (int r = 0; r < 4; r++) {
            int row = q * 4 + r;
            float S = 0.f, Q = 0.f;
#pragma unroll
            for (int ww = 0; ww < 8; ww++) {
                S += pS[ww][row];
                Q += pQ[ww][row];
            }
            float mu = S * (1.f / 128.f);
            float var = Q * (1.f / 128.f) - mu * mu;
            float rs = rsqrtf(var + 1e-5f);
            float y = (acc2[r] - mu) * rs * ng[col2] + nb[col2];
            y = y > 0.f ? y : 0.01f * y;
            yv[r] = y;
            t2[r] = y * y;
        }
#pragma unroll
        for (int off = 1; off < 16; off <<= 1)
#pragma unroll
            for (int r = 0; r < 4; r++) t2[r] += __shfl_xor(t2[r], off, 64);
    }
    __syncthreads();
    if (w < 8 && ln == 0)
#pragma unroll
        for (int r = 0; r < 4; r++) pS[w][q * 4 + r] = t2[r];
    __syncthreads();
    if (w < 8) {
#pragma unroll
        for (int r = 0; r < 4; r++) {
            int row = q * 4 + r;
            float T = 0.f;
#pragma unroll
            for (int ww = 0; ww < 8; ww++) T += pS[ww][row];
            if (w == 0 && ln == 0) rn[row0 + row] = sqrtf(T);
            rout[(size_t)(row0 + row) * 128 + col2] = f2bf(yv[r]);
        }
    }
}

// ---------------- encoder: h = xb @ encW^T + b; LN0 + lrelu (512 thr) ------
__global__ __launch_bounds__(512) void enc_kernel(const ushort* __restrict__ xb,
                                                  const ushort* __restrict__ encWt,
                                                  const float* __restrict__ encB,
                                                  const float* __restrict__ lg,
                                                  const float* __restrict__ lb,
                                                  float* __restrict__ h,
                                                  ushort* __restrict__ rbuf,
                                                  float* __restrict__ rn, int N) {
    __shared__ __align__(16) ushort As[16][136];
    __shared__ float pS[8][16], pQ[8][16];
    uint(*AsU)[68] = (uint(*)[68])As;
    int tid = threadIdx.x, w = tid >> 6, l = tid & 63;
    int q = l >> 4, ln = l & 15;
    int row0 = blockIdx.x * 16;
    for (int idx = tid; idx < 16 * 64; idx += 512) {
        int row = idx >> 6, cl = idx & 63;
        AsU[row][cl] = ((const uint*)xb)[(size_t)(row0 + row) * 64 + cl];
    }
    __syncthreads();
    int col = w * 16 + ln;
    f32x4 acc = (f32x4){0.f, 0.f, 0.f, 0.f};
#pragma unroll
    for (int ks = 0; ks < 128; ks += 32) {
        bf16x8 a = *(const bf16x8*)&As[ln][ks + q * 8];
        bf16x8 bv = *(const bf16x8*)(encWt + (size_t)col * 128 + ks + q * 8);
        acc = __builtin_amdgcn_mfma_f32_16x16x32_bf16(a, bv, acc, 0, 0, 0);
    }
    float s1[4], s2[4];
#pragma unroll
    for (int r = 0; r < 4; r++) {
        int row = q * 4 + r;
        float v = acc[r] + encB[col];
        h[(size_t)(row0 + row) * 128 + col] = v;
        acc[r] = v;
        s1[r] = v;
        s2[r] = v * v;
    }
#pragma unroll
    for (int off = 1; off < 16; off <<= 1)
#pragma unroll
        for (int r = 0; r < 4; r++) {
            s1[r] += __shfl_xor(s1[r], off, 64);
            s2[r] += __shfl_xor(s2[r], off, 64);
        }
    if (ln == 0)
#pragma unroll
        for (int r = 0; r < 4; r++) {
            pS[w][q * 4 + r] = s1[r];
            pQ[w][q * 4 + r] = s2[r];
        }
    __syncthreads();
    float yv[4], t2[4];
#pragma unroll
    for (int r = 0; r < 4; r++) {
        int row = q * 4 + r;
        float S = 0.f, Q = 0.f;
#pragma unroll
        for (int ww = 0; ww < 8; ww++) {
            S += pS[ww][row];
            Q += pQ[ww][row];
        }
        float mu = S * (1.f / 128.f);
        float var = Q * (1.f / 128.f) - mu * mu;
        float rs = rsqrtf(var + 1e-5f);
        float y = (acc[r] - mu) * rs * lg[col] + lb[col];
        y = y > 0.f ? y : 0.01f * y;
        yv[r] = y;
        t2[r] = y * y;
    }
#pragma unroll
    for (int off = 1; off < 16; off <<= 1)
#pragma unroll
        for (int r = 0; r < 4; r++) t2[r] += __shfl_xor(t2[r], off, 64);
    __syncthreads();
    if (ln == 0)
#pragma unroll
        for (int r = 0; r < 4; r++) pS[w][q * 4 + r] = t2[r];
    __syncthreads();
#pragma unroll
    for (int r = 0; r < 4; r++) {
        int row = q * 4 + r;
        float T = 0.f;
#pragma unroll
        for (int ww = 0; ww < 8; ww++) T += pS[ww][row];
        if (w == 0 && ln == 0) rn[row0 + row] = sqrtf(T);
        rbuf[(size_t)(row0 + row) * 128 + col] = f2bf(yv[r]);
    }
}

// ---------------- pool: one block per graph, 4 waves over rows -------------
__global__ __launch_bounds__(256) void pool_kernel(const ushort* __restrict__ rf,
                                                   const int* __restrict__ gstart,
                                                   float* __restrict__ out) {
    __shared__ float pb0[4][64], pb1[4][64];
    int g = blockIdx.x;
    int w = threadIdx.x >> 6, l = threadIdx.x & 63;
    int s = gstart[g], e = gstart[g + 1];
    float a0 = 0.f, a1 = 0.f;
    for (int n = s + w; n < e; n += 4) {
        uint rv = ((const uint*)rf)[(size_t)n * 64 + l];
        a0 += bf2f((ushort)(rv & 0xffff));
        a1 += bf2f((ushort)(rv >> 16));
    }
    pb0[w][l] = a0;
    pb1[w][l] = a1;
    __syncthreads();
    if (threadIdx.x < 64) {
        float t0 = pb0[0][l] + pb0[1][l] + pb0[2][l] + pb0[3][l];
        float t1 = pb1[0][l] + pb1[1][l] + pb1[2][l] + pb1[3][l];
        float inv = 1.f / fmaxf((float)(e - s), 1.f);
        out[g * 128 + 2 * l] = t0 * inv;
        out[g * 128 + 2 * l + 1] = t1 * inv;
    }
}

// ---------------------------------------------------------------------------
extern "C" void kernel_launch(void* const* d_in, const int* in_sizes, int n_in,
                              void* d_out, int out_size, void* d_ws, size_t ws_size,
                              hipStream_t stream) {
    const float* x     = (const float*)d_in[0];
    const int*   ei    = (const int*)d_in[1];
    const int*   batch = (const int*)d_in[2];
    const float* encW  = (const float*)d_in[3];
    const float* encB  = (const float*)d_in[4];
    const float* ln_g  = (const float*)d_in[5];
    const float* ln_b  = (const float*)d_in[6];
    const float* tArr  = (const float*)d_in[7];
    const float* scArr = (const float*)d_in[8];
    const float* W1    = (const float*)d_in[9];
    const float* b1    = (const float*)d_in[10];
    const float* mg    = (const float*)d_in[11];
    const float* mb    = (const float*)d_in[12];
    const float* W2    = (const float*)d_in[13];
    const float* b2    = (const float*)d_in[14];
    const float* fn_g  = (const float*)d_in[15];
    const float* fn_b  = (const float*)d_in[16];
    float* out = (float*)d_out;

    const int N = in_sizes[0] / 128;  // 10000
    const int E = in_sizes[1] / 2;    // 160000
    const int L = in_sizes[7];        // 14
    const int G = 64;

    const int* src = ei;
    const int* dst = ei + E;

    char* p = (char*)d_ws;
    auto alloc = [&](size_t bytes) -> void* {
        void* qp = (void*)p;
        p += (bytes + 255) & ~(size_t)255;
        return qp;
    };
    int*    deg    = (int*)alloc((size_t)N * 4);
    int*    offs   = (int*)alloc((size_t)(N + 1) * 4);
    int*    cursor = (int*)alloc((size_t)N * 4);
    int*    esrc   = (int*)alloc((size_t)E * 4);
    int*    gstart = (int*)alloc((size_t)(G + 1) * 4);
    float*  h      = (float*)alloc((size_t)N * 128 * 4);
    ushort* r0     = (ushort*)alloc((size_t)N * 128 * 2);
    ushort* r1     = (ushort*)alloc((size_t)N * 128 * 2);
    float*  rn     = (float*)alloc((size_t)N * 4);
    ushort* xb     = (ushort*)alloc((size_t)N * 128 * 2);
    ushort* W1t    = (ushort*)alloc((size_t)L * 32768 * 2);
    ushort* W2t    = (ushort*)alloc((size_t)L * 32768 * 2);
    ushort* encWt  = (ushort*)alloc((size_t)16384 * 2);

    (void)hipMemsetAsync(deg, 0, (size_t)N * 4, stream);

    setup_kernel<<<(N * 128 + 255) / 256, 256, 0, stream>>>(x, xb, dst, deg, batch,
                                                            gstart, N * 128, N, E, G);
    scan_kernel<<<1, 1024, 0, stream>>>(deg, offs, cursor, N);
    scatter_kernel<<<(E + 255) / 256, 256, 0, stream>>>(src, dst, cursor, esrc, E);
    prep_kernel<<<dim3(8, 8, 2 * L + 1), 256, 0, stream>>>(W1, W2, encW, W1t, W2t,
                                                           encWt, L);

    const int TILES = N / 16;  // 625

    enc_kernel<<<TILES, 512, 0, stream>>>(xb, encWt, encB, ln_g, ln_b, h, r0, rn, N);

    for (int i = 0; i < L; i++) {
        const ushort* rin = (i & 1) ? r1 : r0;
        ushort* rout = (i & 1) ? r0 : r1;
        const float* ng = (i < L - 1) ? (ln_g + (size_t)(i + 1) * 128) : fn_g;
        const float* nb = (i < L - 1) ? (ln_b + (size_t)(i + 1) * 128) : fn_b;
        layer_kernel<<<TILES, 1024, 0, stream>>>(rin, rout, offs, esrc, rn, h,
                                                 W1t + ((size_t)i << 15),
                                                 W2t + ((size_t)i << 15),
                                                 b1 + (size_t)i * 256,
                                                 mg + (size_t)i * 256,
                                                 mb + (size_t)i * 256,
                                                 b2 + (size_t)i * 128,
                                                 ng, nb, tArr + i, scArr + i, N);
    }

    // last layer i=L-1 wrote rout = ((L-1)&1) ? r0 : r1
    const ushort* rf = ((L - 1) & 1) ? r0 : r1;
    pool_kernel<<<G, 256, 0, stream>>>(rf, gstart, out);
}

// Round 16
// 615.169 us; speedup vs baseline: 1.3251x; 1.3251x over previous
//
#include <hip/hip_runtime.h>
#include <cstdint>
#include <cstddef>

// ---------------------------------------------------------------------------
// DeeperGCN forward on MI355X. Round 16 (= round 15 resubmitted; previous
// round hit GPUAcquisitionTimeout — no measurement). Round 13 base (586 us) +
// (1) LPT tile scheduling: tiles ranked by max node degree, heavy tiles
//     dispatched first via order[] permutation (CSR fixed across layers);
// (2) own-row + rn prefetch hoisted above the gather loop in agg.
// Layer: 512 thr / 8 waves, 2 nodes/wave, half-wave uint2 gathers (8 edges
// in flight), max-free softmax (bounded z -> fp32 exp safe), 16-row tiles.
// N=10000 nodes, E=160000 edges, H=128, L=14 layers, G=64 graphs.
// ---------------------------------------------------------------------------

#define BT 512  // 8 waves

typedef __attribute__((ext_vector_type(8))) short bf16x8;
typedef __attribute__((ext_vector_type(4))) float f32x4;

__device__ inline float bf2f(ushort u) {
    union { uint i; float f; } v;
    v.i = (uint)u << 16;
    return v.f;
}
__device__ inline ushort f2bf(float f) {
    union { float f; uint i; } v;
    v.f = f;
    return (ushort)((v.i + 0x7fffu + ((v.i >> 16) & 1u)) >> 16);
}
__device__ inline uint f2bf2(float a, float b) {
    return (uint)f2bf(a) | ((uint)f2bf(b) << 16);
}

__device__ inline float wave_sum_f(float v) {
#pragma unroll
    for (int off = 32; off > 0; off >>= 1) v += __shfl_xor(v, off, 64);
    return v;
}

// ---------------- setup: xb convert + deg histogram + graph boundaries -----
__global__ void setup_kernel(const float* __restrict__ x, ushort* __restrict__ xb,
                             const int* __restrict__ dst, int* __restrict__ deg,
                             const int* __restrict__ batch, int* __restrict__ gstart,
                             int total, int N, int E, int G) {
    int idx = blockIdx.x * blockDim.x + threadIdx.x;
    if (idx >= total) return;
    xb[idx] = f2bf(x[idx]);
    if (idx < E) atomicAdd(&deg[dst[idx]], 1);
    if (idx < N) {
        int bb = batch[idx];
        if (idx == 0)
            for (int g = 0; g <= bb; g++) gstart[g] = 0;
        else {
            int pb = batch[idx - 1];
            for (int g = pb + 1; g <= bb; g++) gstart[g] = idx;
        }
        if (idx == N - 1)
            for (int g = bb + 1; g <= G; g++) gstart[g] = N;
    }
}

// single-workgroup exclusive scan of deg -> offs, cursor
__global__ __launch_bounds__(1024) void scan_kernel(const int* __restrict__ deg,
                                                    int* __restrict__ offs,
                                                    int* __restrict__ cursor, int N) {
    __shared__ int part[1024];
    int tid = threadIdx.x;
    int CH = (N + 1023) / 1024;
    int base = tid * CH;
    int s = 0;
    for (int i = 0; i < CH; i++) {
        int idx = base + i;
        if (idx < N) s += deg[idx];
    }
    part[tid] = s;
    __syncthreads();
    for (int off = 1; off < 1024; off <<= 1) {
        int v = (tid >= off) ? part[tid - off] : 0;
        __syncthreads();
        part[tid] += v;
        __syncthreads();
    }
    int run = (tid == 0) ? 0 : part[tid - 1];
    for (int i = 0; i < CH; i++) {
        int idx = base + i;
        if (idx < N) {
            offs[idx] = run;
            cursor[idx] = run;
            run += deg[idx];
        }
    }
    if (tid == 1023) offs[N] = part[1023];
}

__global__ void scatter_kernel(const int* __restrict__ src, const int* __restrict__ dst,
                               int* __restrict__ cursor, int* __restrict__ esrc, int E) {
    int e = blockIdx.x * blockDim.x + threadIdx.x;
    if (e < E) {
        int d = dst[e];
        int pos = atomicAdd(&cursor[d], 1);
        esrc[pos] = src[e];
    }
}

// ---- tile scheduling: rank 625 tiles by descending max node degree --------
// order[rank] = tile; bijective (ties broken by tile index).
__global__ __launch_bounds__(1024) void order_kernel(const int* __restrict__ offs,
                                                     int* __restrict__ order, int T) {
    __shared__ int wts[640];
    int t = threadIdx.x;
    if (t < T) {
        int mx = 0, base = t * 16;
#pragma unroll 1
        for (int k = 0; k < 16; k++) mx = max(mx, offs[base + k + 1] - offs[base + k]);
        wts[t] = mx;
    }
    __syncthreads();
    if (t < T) {
        int wv = wts[t], rank = 0;
#pragma unroll 1
        for (int j = 0; j < T; j++) {
            int wj = wts[j];
            if (wj > wv || (wj == wv && j < t)) rank++;
        }
        order[rank] = t;
    }
}

// ---------------- weight prep: fp32 [R][C] -> bf16 [C][R], all matrices ----
__global__ __launch_bounds__(256) void prep_kernel(const float* __restrict__ W1,
                                                   const float* __restrict__ W2,
                                                   const float* __restrict__ encW,
                                                   ushort* __restrict__ W1t,
                                                   ushort* __restrict__ W2t,
                                                   ushort* __restrict__ encWt, int L) {
    __shared__ float tile[32][33];
    int z = blockIdx.z;
    const float* in;
    ushort* out;
    int R, C;
    if (z < L) {
        in = W1 + (size_t)z * 32768; out = W1t + (size_t)z * 32768; R = 128; C = 256;
    } else if (z < 2 * L) {
        int i = z - L;
        in = W2 + (size_t)i * 32768; out = W2t + (size_t)i * 32768; R = 256; C = 128;
    } else {
        in = encW; out = encWt; R = 128; C = 128;
    }
    int r0 = blockIdx.y * 32, c0 = blockIdx.x * 32;
    if (r0 >= R || c0 >= C) return;
    int tx = threadIdx.x & 31, ty = threadIdx.x >> 5;
    for (int i = ty; i < 32; i += 8) tile[i][tx] = in[(size_t)(r0 + i) * C + c0 + tx];
    __syncthreads();
    for (int i = ty; i < 32; i += 8)
        out[(size_t)(c0 + i) * R + r0 + tx] = f2bf(tile[tx][i]);
}

// ---- aggregation v15: 2 nodes/wave; wave-preloaded indices + half-wave
// uint2 gathers (8 edges in flight); own-row/rn prefetched above the loop. --
__device__ __forceinline__ void agg_stage_v15(const ushort* __restrict__ rin,
                                              const int* __restrict__ offs,
                                              const int* __restrict__ esrc,
                                              const float* __restrict__ rnbuf,
                                              float tv, float sv, int row0,
                                              int w, int l, uint (*AsU)[68]) {
    const uint2* rin2 = (const uint2*)rin;
    int nd0 = row0 + 2 * w;
    int half = l >> 5, li = l & 31;
    int a0 = offs[nd0], a1 = offs[nd0 + 1], a2 = offs[nd0 + 2];
    int eb[2] = {a0, a1};
    int dg[2] = {a1 - a0, a2 - a1};

    // prefetch (independent of gather loop): own rows + rn for both nodes
    uint2 ru0 = rin2[(size_t)nd0 * 32 + li];
    uint2 ru1 = rin2[(size_t)(nd0 + 1) * 32 + li];
    float rn0 = rnbuf[nd0], rn1 = rnbuf[nd0 + 1];

    float s[2][4] = {}, W[2][4] = {};
    int mxdeg = max(dg[0], dg[1]);

#pragma unroll 1
    for (int base = 0; base < mxdeg; base += 64) {
        int rem0 = min(dg[0] - base, 64);
        int rem1 = min(dg[1] - base, 64);
        int idx0 = (rem0 > 0 && l < rem0) ? esrc[eb[0] + base + l] : 0;
        int idx1 = (rem1 > 0 && l < rem1) ? esrc[eb[1] + base + l] : 0;
        int it = (max(rem0, rem1) + 7) >> 3;
#pragma unroll 1
        for (int i = 0; i < it; i++) {
            int j0 = i * 8 + half;
            uint2 rv[2][4];
            bool vl[2][4];
#pragma unroll
            for (int c = 0; c < 4; c++) {
                int j = j0 + 2 * c;
                vl[0][c] = j < rem0;
                vl[1][c] = j < rem1;
                int sn0 = __shfl(idx0, j, 64);
                int sn1 = __shfl(idx1, j, 64);
                if (vl[0][c]) rv[0][c] = rin2[(size_t)sn0 * 32 + li];
                if (vl[1][c]) rv[1][c] = rin2[(size_t)sn1 * 32 + li];
            }
#pragma unroll
            for (int k = 0; k < 2; k++)
#pragma unroll
                for (int c = 0; c < 4; c++) {
                    if (vl[k][c]) {
                        float f0 = bf2f((ushort)(rv[k][c].x & 0xffff));
                        float f1 = bf2f((ushort)(rv[k][c].x >> 16));
                        float f2 = bf2f((ushort)(rv[k][c].y & 0xffff));
                        float f3 = bf2f((ushort)(rv[k][c].y >> 16));
                        float g0 = fmaxf(f0, 0.f) + 1e-7f;
                        float g1 = fmaxf(f1, 0.f) + 1e-7f;
                        float g2 = fmaxf(f2, 0.f) + 1e-7f;
                        float g3 = fmaxf(f3, 0.f) + 1e-7f;
                        float p0 = __expf(g0 * tv);
                        float p1 = __expf(g1 * tv);
                        float p2 = __expf(g2 * tv);
                        float p3 = __expf(g3 * tv);
                        s[k][0] += p0; W[k][0] += g0 * p0;
                        s[k][1] += p1; W[k][1] += g1 * p1;
                        s[k][2] += p2; W[k][2] += g2 * p2;
                        s[k][3] += p3; W[k][3] += g3 * p3;
                    }
                }
        }
    }

    // merge halves (associative sums), then per-node epilogue
#pragma unroll
    for (int k = 0; k < 2; k++) {
#pragma unroll
        for (int f = 0; f < 4; f++) {
            s[k][f] += __shfl_xor(s[k][f], 32, 64);
            W[k][f] += __shfl_xor(W[k][f], 32, 64);
        }
        float agg[4], nsq = 0.f;
#pragma unroll
        for (int f = 0; f < 4; f++) {
            agg[f] = W[k][f] / (s[k][f] + 1e-16f);
            nsq += agg[f] * agg[f];
        }
#pragma unroll
        for (int off = 1; off < 32; off <<= 1) nsq += __shfl_xor(nsq, off, 64);
        float rnv = (k == 0) ? rn0 : rn1;
        uint2 ru = (k == 0) ? ru0 : ru1;
        float fac = rnv * sv / fmaxf(sqrtf(nsq), 1e-12f);
        if (half == 0) {
            uint2 o;
            o.x = f2bf2(bf2f((ushort)(ru.x & 0xffff)) + agg[0] * fac,
                        bf2f((ushort)(ru.x >> 16)) + agg[1] * fac);
            o.y = f2bf2(bf2f((ushort)(ru.y & 0xffff)) + agg[2] * fac,
                        bf2f((ushort)(ru.y >> 16)) + agg[3] * fac);
            *(uint2*)&AsU[2 * w + k][2 * li] = o;
        }
    }
}

// ---- gemm1 (8 waves): z1 = relu(LN256(A(16x128) @ W1^T + b1)) into LDS ----
__device__ __forceinline__ void gemm1_stage8(const ushort (*As)[136],
                                             const ushort* __restrict__ Bt,
                                             const float* __restrict__ bias,
                                             const float* __restrict__ mg,
                                             const float* __restrict__ mb,
                                             ushort (*z1s)[264],
                                             int w, int q, int ln,
                                             float (*pS)[16], float (*pQ)[16]) {
    f32x4 acc[2];
    acc[0] = (f32x4){0.f, 0.f, 0.f, 0.f};
    acc[1] = (f32x4){0.f, 0.f, 0.f, 0.f};
#pragma unroll
    for (int ks = 0; ks < 128; ks += 32) {
        bf16x8 a = *(const bf16x8*)&As[ln][ks + q * 8];
#pragma unroll
        for (int ct = 0; ct < 2; ct++) {
            bf16x8 bv = *(const bf16x8*)(Bt + (size_t)(w * 32 + ct * 16 + ln) * 128 + ks + q * 8);
            acc[ct] = __builtin_amdgcn_mfma_f32_16x16x32_bf16(a, bv, acc[ct], 0, 0, 0);
        }
    }
    float s1[4] = {0, 0, 0, 0}, s2[4] = {0, 0, 0, 0};
#pragma unroll
    for (int ct = 0; ct < 2; ct++)
#pragma unroll
        for (int r = 0; r < 4; r++) {
            float v = acc[ct][r] + bias[w * 32 + ct * 16 + ln];
            acc[ct][r] = v;
            s1[r] += v;
            s2[r] += v * v;
        }
#pragma unroll
    for (int off = 1; off < 16; off <<= 1)
#pragma unroll
        for (int r = 0; r < 4; r++) {
            s1[r] += __shfl_xor(s1[r], off, 64);
            s2[r] += __shfl_xor(s2[r], off, 64);
        }
    if (ln == 0)
#pragma unroll
        for (int r = 0; r < 4; r++) {
            pS[w][q * 4 + r] = s1[r];
            pQ[w][q * 4 + r] = s2[r];
        }
    __syncthreads();
#pragma unroll
    for (int r = 0; r < 4; r++) {
        int row = q * 4 + r;
        float S = 0.f, Q = 0.f;
#pragma unroll
        for (int ww = 0; ww < 8; ww++) {
            S += pS[ww][row];
            Q += pQ[ww][row];
        }
        float mu = S * (1.f / 256.f);
        float var = Q * (1.f / 256.f) - mu * mu;
        float rs = rsqrtf(var + 1e-5f);
#pragma unroll
        for (int ct = 0; ct < 2; ct++) {
            int col = w * 32 + ct * 16 + ln;
            float y = (acc[ct][r] - mu) * rs * mg[col] + mb[col];
            z1s[row][col] = f2bf(fmaxf(y, 0.f));
        }
    }
    __syncthreads();
}

// ---- out gemm (8 waves): v = A(16xKD)@B^T + bias (+h); h=v; LN128+lrelu ---
template <int KD, bool RESID>
__device__ __forceinline__ void out_stage8(const ushort* __restrict__ Abase, int astr,
                                           const ushort* __restrict__ Bt,
                                           const float* __restrict__ bias,
                                           const float* __restrict__ lg,
                                           const float* __restrict__ lb,
                                           float* __restrict__ hbuf,
                                           ushort* __restrict__ rout,
                                           float* __restrict__ rnbuf,
                                           int row0, int w, int q, int ln,
                                           float (*pS)[16], float (*pQ)[16]) {
    f32x4 acc = (f32x4){0.f, 0.f, 0.f, 0.f};
    int col = w * 16 + ln;
#pragma unroll
    for (int ks = 0; ks < KD; ks += 32) {
        bf16x8 a = *(const bf16x8*)(Abase + ln * astr + ks + q * 8);
        bf16x8 bv = *(const bf16x8*)(Bt + (size_t)col * KD + ks + q * 8);
        acc = __builtin_amdgcn_mfma_f32_16x16x32_bf16(a, bv, acc, 0, 0, 0);
    }
    float s1[4], s2[4];
#pragma unroll
    for (int r = 0; r < 4; r++) {
        int row = q * 4 + r;
        float v = acc[r] + bias[col];
        if (RESID) v += hbuf[(size_t)(row0 + row) * 128 + col];
        hbuf[(size_t)(row0 + row) * 128 + col] = v;
        acc[r] = v;
        s1[r] = v;
        s2[r] = v * v;
    }
#pragma unroll
    for (int off = 1; off < 16; off <<= 1)
#pragma unroll
        for (int r = 0; r < 4; r++) {
            s1[r] += __shfl_xor(s1[r], off, 64);
            s2[r] += __shfl_xor(s2[r], off, 64);
        }
    if (ln == 0)
#pragma unroll
        for (int r = 0; r < 4; r++) {
            pS[w][q * 4 + r] = s1[r];
            pQ[w][q * 4 + r] = s2[r];
        }
    __syncthreads();
    float yv[4];
    float t2[4];
#pragma unroll
    for (int r = 0; r < 4; r++) {
        int row = q * 4 + r;
        float S = 0.f, Q = 0.f;
#pragma unroll
        for (int ww = 0; ww < 8; ww++) {
            S += pS[ww][row];
            Q += pQ[ww][row];
        }
        float mu = S * (1.f / 128.f);
        float var = Q * (1.f / 128.f) - mu * mu;
        float rs = rsqrtf(var + 1e-5f);
        float y = (acc[r] - mu) * rs * lg[col] + lb[col];
        y = y > 0.f ? y : 0.01f * y;
        yv[r] = y;
        t2[r] = y * y;
    }
#pragma unroll
    for (int off = 1; off < 16; off <<= 1)
#pragma unroll
        for (int r = 0; r < 4; r++) t2[r] += __shfl_xor(t2[r], off, 64);
    __syncthreads();
    if (ln == 0)
#pragma unroll
        for (int r = 0; r < 4; r++) pS[w][q * 4 + r] = t2[r];
    __syncthreads();
#pragma unroll
    for (int r = 0; r < 4; r++) {
        int row = q * 4 + r;
        float T = 0.f;
#pragma unroll
        for (int ww = 0; ww < 8; ww++) T += pS[ww][row];
        if (w == 0 && ln == 0) rnbuf[row0 + row] = sqrtf(T);
        rout[(size_t)(row0 + row) * 128 + col] = f2bf(yv[r]);
    }
}

// ---------------- encoder: h = xb @ encW^T + b; LN0 + lrelu ----------------
__global__ __launch_bounds__(BT) void enc_kernel(const ushort* __restrict__ xb,
                                                 const ushort* __restrict__ encWt,
                                                 const float* __restrict__ encB,
                                                 const float* __restrict__ lg,
                                                 const float* __restrict__ lb,
                                                 float* __restrict__ h,
                                                 ushort* __restrict__ rbuf,
                                                 float* __restrict__ rn, int N) {
    __shared__ __align__(16) ushort As[16][136];
    __shared__ float pS[8][16], pQ[8][16];
    uint(*AsU)[68] = (uint(*)[68])As;
    int tid = threadIdx.x, w = tid >> 6, l = tid & 63;
    int q = l >> 4, ln = l & 15;
    int row0 = blockIdx.x * 16;
    for (int idx = tid; idx < 16 * 64; idx += BT) {
        int row = idx >> 6, cl = idx & 63;
        AsU[row][cl] = ((const uint*)xb)[(size_t)(row0 + row) * 64 + cl];
    }
    __syncthreads();
    out_stage8<128, false>(&As[0][0], 136, encWt, encB, lg, lb, h, rbuf, rn,
                           row0, w, q, ln, pS, pQ);
}

// ---------------- fused layer: 16-row tile (LPT-ordered), agg+gemm1+gemm2 --
__global__ __launch_bounds__(BT) void layer_kernel(const ushort* __restrict__ rin,
                                                   ushort* __restrict__ rout,
                                                   const int* __restrict__ offs,
                                                   const int* __restrict__ esrc,
                                                   const int* __restrict__ order,
                                                   float* __restrict__ rn,
                                                   float* __restrict__ h,
                                                   const ushort* __restrict__ W1t,
                                                   const ushort* __restrict__ W2t,
                                                   const float* __restrict__ b1,
                                                   const float* __restrict__ mg,
                                                   const float* __restrict__ mb,
                                                   const float* __restrict__ b2,
                                                   const float* __restrict__ ng,
                                                   const float* __restrict__ nb,
                                                   const float* __restrict__ tptr,
                                                   const float* __restrict__ scptr,
                                                   int N) {
    __shared__ __align__(16) ushort As[16][136];
    __shared__ __align__(16) ushort z1s[16][264];
    __shared__ float pS[8][16], pQ[8][16];
    uint(*AsU)[68] = (uint(*)[68])As;
    int tid = threadIdx.x, w = tid >> 6, l = tid & 63;
    int q = l >> 4, ln = l & 15;
    int row0 = order[blockIdx.x] * 16;
    float tv = *tptr, sv = *scptr;
    agg_stage_v15(rin, offs, esrc, rn, tv, sv, row0, w, l, AsU);
    __syncthreads();
    gemm1_stage8(As, W1t, b1, mg, mb, z1s, w, q, ln, pS, pQ);
    out_stage8<256, true>(&z1s[0][0], 264, W2t, b2, ng, nb, h, rout, rn,
                          row0, w, q, ln, pS, pQ);
}

// ---------------- pool: one block per graph, 4 waves over rows -------------
__global__ __launch_bounds__(256) void pool_kernel(const ushort* __restrict__ rf,
                                                   const int* __restrict__ gstart,
                                                   float* __restrict__ out) {
    __shared__ float pb0[4][64], pb1[4][64];
    int g = blockIdx.x;
    int w = threadIdx.x >> 6, l = threadIdx.x & 63;
    int s = gstart[g], e = gstart[g + 1];
    float a0 = 0.f, a1 = 0.f;
    for (int n = s + w; n < e; n += 4) {
        uint rv = ((const uint*)rf)[(size_t)n * 64 + l];
        a0 += bf2f((ushort)(rv & 0xffff));
        a1 += bf2f((ushort)(rv >> 16));
    }
    pb0[w][l] = a0;
    pb1[w][l] = a1;
    __syncthreads();
    if (threadIdx.x < 64) {
        float t0 = pb0[0][l] + pb0[1][l] + pb0[2][l] + pb0[3][l];
        float t1 = pb1[0][l] + pb1[1][l] + pb1[2][l] + pb1[3][l];
        float inv = 1.f / fmaxf((float)(e - s), 1.f);
        out[g * 128 + 2 * l] = t0 * inv;
        out[g * 128 + 2 * l + 1] = t1 * inv;
    }
}

// ---------------------------------------------------------------------------
extern "C" void kernel_launch(void* const* d_in, const int* in_sizes, int n_in,
                              void* d_out, int out_size, void* d_ws, size_t ws_size,
                              hipStream_t stream) {
    const float* x     = (const float*)d_in[0];
    const int*   ei    = (const int*)d_in[1];
    const int*   batch = (const int*)d_in[2];
    const float* encW  = (const float*)d_in[3];
    const float* encB  = (const float*)d_in[4];
    const float* ln_g  = (const float*)d_in[5];
    const float* ln_b  = (const float*)d_in[6];
    const float* tArr  = (const float*)d_in[7];
    const float* scArr = (const float*)d_in[8];
    const float* W1    = (const float*)d_in[9];
    const float* b1    = (const float*)d_in[10];
    const float* mg    = (const float*)d_in[11];
    const float* mb    = (const float*)d_in[12];
    const float* W2    = (const float*)d_in[13];
    const float* b2    = (const float*)d_in[14];
    const float* fn_g  = (const float*)d_in[15];
    const float* fn_b  = (const float*)d_in[16];
    float* out = (float*)d_out;

    const int N = in_sizes[0] / 128;  // 10000
    const int E = in_sizes[1] / 2;    // 160000
    const int L = in_sizes[7];        // 14
    const int G = 64;

    const int* src = ei;
    const int* dst = ei + E;

    char* p = (char*)d_ws;
    auto alloc = [&](size_t bytes) -> void* {
        void* qp = (void*)p;
        p += (bytes + 255) & ~(size_t)255;
        return qp;
    };
    int*    deg    = (int*)alloc((size_t)N * 4);
    int*    offs   = (int*)alloc((size_t)(N + 1) * 4);
    int*    cursor = (int*)alloc((size_t)N * 4);
    int*    esrc   = (int*)alloc((size_t)E * 4);
    int*    gstart = (int*)alloc((size_t)(G + 1) * 4);
    int*    order  = (int*)alloc((size_t)1024 * 4);
    float*  h      = (float*)alloc((size_t)N * 128 * 4);
    ushort* r0     = (ushort*)alloc((size_t)N * 128 * 2);
    ushort* r1     = (ushort*)alloc((size_t)N * 128 * 2);
    float*  rn     = (float*)alloc((size_t)N * 4);
    ushort* xb     = (ushort*)alloc((size_t)N * 128 * 2);
    ushort* W1t    = (ushort*)alloc((size_t)L * 32768 * 2);
    ushort* W2t    = (ushort*)alloc((size_t)L * 32768 * 2);
    ushort* encWt  = (ushort*)alloc((size_t)16384 * 2);

    (void)hipMemsetAsync(deg, 0, (size_t)N * 4, stream);

    setup_kernel<<<(N * 128 + 255) / 256, 256, 0, stream>>>(x, xb, dst, deg, batch,
                                                            gstart, N * 128, N, E, G);
    scan_kernel<<<1, 1024, 0, stream>>>(deg, offs, cursor, N);
    scatter_kernel<<<(E + 255) / 256, 256, 0, stream>>>(src, dst, cursor, esrc, E);
    prep_kernel<<<dim3(8, 8, 2 * L + 1), 256, 0, stream>>>(W1, W2, encW, W1t, W2t,
                                                           encWt, L);

    const int TILES = N / 16;  // 625
    order_kernel<<<1, 1024, 0, stream>>>(offs, order, TILES);

    enc_kernel<<<TILES, BT, 0, stream>>>(xb, encWt, encB, ln_g, ln_b, h, r0, rn, N);

    for (int i = 0; i < L; i++) {
        const ushort* rin = (i & 1) ? r1 : r0;
        ushort* rout = (i & 1) ? r0 : r1;
        const float* ng = (i < L - 1) ? (ln_g + (size_t)(i + 1) * 128) : fn_g;
        const float* nb = (i < L - 1) ? (ln_b + (size_t)(i + 1) * 128) : fn_b;
        layer_kernel<<<TILES, BT, 0, stream>>>(rin, rout, offs, esrc, order, rn, h,
                                               W1t + ((size_t)i << 15),
                                               W2t + ((size_t)i << 15),
                                               b1 + (size_t)i * 256,
                                               mg + (size_t)i * 256,
                                               mb + (size_t)i * 256,
                                               b2 + (size_t)i * 128,
                                               ng, nb, tArr + i, scArr + i, N);
    }

    // last layer i=L-1 wrote rout = ((L-1)&1) ? r0 : r1
    const ushort* rf = ((L - 1) & 1) ? r0 : r1;
    pool_kernel<<<G, 256, 0, stream>>>(rf, gstart, out);
}

// Round 18
// 579.032 us; speedup vs baseline: 1.4078x; 1.0624x over previous
//
#include <hip/hip_runtime.h>
#include <cstdint>
#include <cstddef>

// ---------------------------------------------------------------------------
// DeeperGCN forward on MI355X. Round 18 (= round 17 with __exp2f -> 
// __builtin_amdgcn_exp2f; glibc macro collision broke compile). Round 13
// base (best, 586 us) + own-row/rn prefetch + exp2 fold (tv2 = tv*log2e ->
// bare v_exp_f32, one v_mul less per exp). NO LPT ordering (round 16
// regressed 5%: order[] indirection + L2-locality loss).
// Layer: 512 thr / 8 waves, 2 nodes/wave, wave-preloaded indices + half-wave
// uint2 gathers (8 edges in flight), max-free softmax (bounded z -> fp32 exp
// safe), 16-row tiles, 625 blocks.
// N=10000 nodes, E=160000 edges, H=128, L=14 layers, G=64 graphs.
// ---------------------------------------------------------------------------

#define BT 512  // 8 waves

typedef __attribute__((ext_vector_type(8))) short bf16x8;
typedef __attribute__((ext_vector_type(4))) float f32x4;

__device__ inline float bf2f(ushort u) {
    union { uint i; float f; } v;
    v.i = (uint)u << 16;
    return v.f;
}
__device__ inline ushort f2bf(float f) {
    union { float f; uint i; } v;
    v.f = f;
    return (ushort)((v.i + 0x7fffu + ((v.i >> 16) & 1u)) >> 16);
}
__device__ inline uint f2bf2(float a, float b) {
    return (uint)f2bf(a) | ((uint)f2bf(b) << 16);
}
__device__ inline float fast_exp2(float x) {
    return __builtin_amdgcn_exp2f(x);  // v_exp_f32: D = 2^S0
}

__device__ inline float wave_sum_f(float v) {
#pragma unroll
    for (int off = 32; off > 0; off >>= 1) v += __shfl_xor(v, off, 64);
    return v;
}

// ---------------- setup: xb convert + deg histogram + graph boundaries -----
__global__ void setup_kernel(const float* __restrict__ x, ushort* __restrict__ xb,
                             const int* __restrict__ dst, int* __restrict__ deg,
                             const int* __restrict__ batch, int* __restrict__ gstart,
                             int total, int N, int E, int G) {
    int idx = blockIdx.x * blockDim.x + threadIdx.x;
    if (idx >= total) return;
    xb[idx] = f2bf(x[idx]);
    if (idx < E) atomicAdd(&deg[dst[idx]], 1);
    if (idx < N) {
        int bb = batch[idx];
        if (idx == 0)
            for (int g = 0; g <= bb; g++) gstart[g] = 0;
        else {
            int pb = batch[idx - 1];
            for (int g = pb + 1; g <= bb; g++) gstart[g] = idx;
        }
        if (idx == N - 1)
            for (int g = bb + 1; g <= G; g++) gstart[g] = N;
    }
}

// single-workgroup exclusive scan of deg -> offs, cursor
__global__ __launch_bounds__(1024) void scan_kernel(const int* __restrict__ deg,
                                                    int* __restrict__ offs,
                                                    int* __restrict__ cursor, int N) {
    __shared__ int part[1024];
    int tid = threadIdx.x;
    int CH = (N + 1023) / 1024;
    int base = tid * CH;
    int s = 0;
    for (int i = 0; i < CH; i++) {
        int idx = base + i;
        if (idx < N) s += deg[idx];
    }
    part[tid] = s;
    __syncthreads();
    for (int off = 1; off < 1024; off <<= 1) {
        int v = (tid >= off) ? part[tid - off] : 0;
        __syncthreads();
        part[tid] += v;
        __syncthreads();
    }
    int run = (tid == 0) ? 0 : part[tid - 1];
    for (int i = 0; i < CH; i++) {
        int idx = base + i;
        if (idx < N) {
            offs[idx] = run;
            cursor[idx] = run;
            run += deg[idx];
        }
    }
    if (tid == 1023) offs[N] = part[1023];
}

__global__ void scatter_kernel(const int* __restrict__ src, const int* __restrict__ dst,
                               int* __restrict__ cursor, int* __restrict__ esrc, int E) {
    int e = blockIdx.x * blockDim.x + threadIdx.x;
    if (e < E) {
        int d = dst[e];
        int pos = atomicAdd(&cursor[d], 1);
        esrc[pos] = src[e];
    }
}

// ---------------- weight prep: fp32 [R][C] -> bf16 [C][R], all matrices ----
__global__ __launch_bounds__(256) void prep_kernel(const float* __restrict__ W1,
                                                   const float* __restrict__ W2,
                                                   const float* __restrict__ encW,
                                                   ushort* __restrict__ W1t,
                                                   ushort* __restrict__ W2t,
                                                   ushort* __restrict__ encWt, int L) {
    __shared__ float tile[32][33];
    int z = blockIdx.z;
    const float* in;
    ushort* out;
    int R, C;
    if (z < L) {
        in = W1 + (size_t)z * 32768; out = W1t + (size_t)z * 32768; R = 128; C = 256;
    } else if (z < 2 * L) {
        int i = z - L;
        in = W2 + (size_t)i * 32768; out = W2t + (size_t)i * 32768; R = 256; C = 128;
    } else {
        in = encW; out = encWt; R = 128; C = 128;
    }
    int r0 = blockIdx.y * 32, c0 = blockIdx.x * 32;
    if (r0 >= R || c0 >= C) return;
    int tx = threadIdx.x & 31, ty = threadIdx.x >> 5;
    for (int i = ty; i < 32; i += 8) tile[i][tx] = in[(size_t)(r0 + i) * C + c0 + tx];
    __syncthreads();
    for (int i = ty; i < 32; i += 8)
        out[(size_t)(c0 + i) * R + r0 + tx] = f2bf(tile[tx][i]);
}

// ---- aggregation v18: 2 nodes/wave; wave-preloaded indices + half-wave
// uint2 gathers (8 edges in flight); own-row/rn prefetched; exp2-folded. ----
__device__ __forceinline__ void agg_stage_v18(const ushort* __restrict__ rin,
                                              const int* __restrict__ offs,
                                              const int* __restrict__ esrc,
                                              const float* __restrict__ rnbuf,
                                              float tv2, float sv,
                                              int row0, int w, int l,
                                              uint (*AsU)[68]) {
    const uint2* rin2 = (const uint2*)rin;
    int nd0 = row0 + 2 * w;
    int half = l >> 5, li = l & 31;
    int a0 = offs[nd0], a1 = offs[nd0 + 1], a2 = offs[nd0 + 2];
    int eb[2] = {a0, a1};
    int dg[2] = {a1 - a0, a2 - a1};

    // prefetch (independent of gather loop): own rows + rn for both nodes
    uint2 ru0 = rin2[(size_t)nd0 * 32 + li];
    uint2 ru1 = rin2[(size_t)(nd0 + 1) * 32 + li];
    float rn0 = rnbuf[nd0], rn1 = rnbuf[nd0 + 1];

    float s[2][4] = {}, W[2][4] = {};
    int mxdeg = max(dg[0], dg[1]);

#pragma unroll 1
    for (int base = 0; base < mxdeg; base += 64) {
        int rem0 = min(dg[0] - base, 64);
        int rem1 = min(dg[1] - base, 64);
        int idx0 = (rem0 > 0 && l < rem0) ? esrc[eb[0] + base + l] : 0;
        int idx1 = (rem1 > 0 && l < rem1) ? esrc[eb[1] + base + l] : 0;
        int it = (max(rem0, rem1) + 7) >> 3;
#pragma unroll 1
        for (int i = 0; i < it; i++) {
            int j0 = i * 8 + half;
            uint2 rv[2][4];
            bool vl[2][4];
#pragma unroll
            for (int c = 0; c < 4; c++) {
                int j = j0 + 2 * c;
                vl[0][c] = j < rem0;
                vl[1][c] = j < rem1;
                int sn0 = __shfl(idx0, j, 64);
                int sn1 = __shfl(idx1, j, 64);
                if (vl[0][c]) rv[0][c] = rin2[(size_t)sn0 * 32 + li];
                if (vl[1][c]) rv[1][c] = rin2[(size_t)sn1 * 32 + li];
            }
#pragma unroll
            for (int k = 0; k < 2; k++)
#pragma unroll
                for (int c = 0; c < 4; c++) {
                    if (vl[k][c]) {
                        float f0 = bf2f((ushort)(rv[k][c].x & 0xffff));
                        float f1 = bf2f((ushort)(rv[k][c].x >> 16));
                        float f2 = bf2f((ushort)(rv[k][c].y & 0xffff));
                        float f3 = bf2f((ushort)(rv[k][c].y >> 16));
                        float g0 = fmaxf(f0, 0.f) + 1e-7f;
                        float g1 = fmaxf(f1, 0.f) + 1e-7f;
                        float g2 = fmaxf(f2, 0.f) + 1e-7f;
                        float g3 = fmaxf(f3, 0.f) + 1e-7f;
                        // exp(g*tv) == exp2(g*tv*log2e) — tv2 prefolded
                        float p0 = fast_exp2(g0 * tv2);
                        float p1 = fast_exp2(g1 * tv2);
                        float p2 = fast_exp2(g2 * tv2);
                        float p3 = fast_exp2(g3 * tv2);
                        s[k][0] += p0; W[k][0] += g0 * p0;
                        s[k][1] += p1; W[k][1] += g1 * p1;
                        s[k][2] += p2; W[k][2] += g2 * p2;
                        s[k][3] += p3; W[k][3] += g3 * p3;
                    }
                }
        }
    }

    // merge halves (associative sums), then per-node epilogue
#pragma unroll
    for (int k = 0; k < 2; k++) {
#pragma unroll
        for (int f = 0; f < 4; f++) {
            s[k][f] += __shfl_xor(s[k][f], 32, 64);
            W[k][f] += __shfl_xor(W[k][f], 32, 64);
        }
        float agg[4], nsq = 0.f;
#pragma unroll
        for (int f = 0; f < 4; f++) {
            agg[f] = W[k][f] / (s[k][f] + 1e-16f);
            nsq += agg[f] * agg[f];
        }
#pragma unroll
        for (int off = 1; off < 32; off <<= 1) nsq += __shfl_xor(nsq, off, 64);
        float rnv = (k == 0) ? rn0 : rn1;
        uint2 ru = (k == 0) ? ru0 : ru1;
        float fac = rnv * sv / fmaxf(sqrtf(nsq), 1e-12f);
        if (half == 0) {
            uint2 o;
            o.x = f2bf2(bf2f((ushort)(ru.x & 0xffff)) + agg[0] * fac,
                        bf2f((ushort)(ru.x >> 16)) + agg[1] * fac);
            o.y = f2bf2(bf2f((ushort)(ru.y & 0xffff)) + agg[2] * fac,
                        bf2f((ushort)(ru.y >> 16)) + agg[3] * fac);
            *(uint2*)&AsU[2 * w + k][2 * li] = o;
        }
    }
}

// ---- gemm1 (8 waves): z1 = relu(LN256(A(16x128) @ W1^T + b1)) into LDS ----
__device__ __forceinline__ void gemm1_stage8(const ushort (*As)[136],
                                             const ushort* __restrict__ Bt,
                                             const float* __restrict__ bias,
                                             const float* __restrict__ mg,
                                             const float* __restrict__ mb,
                                             ushort (*z1s)[264],
                                             int w, int q, int ln,
                                             float (*pS)[16], float (*pQ)[16]) {
    f32x4 acc[2];
    acc[0] = (f32x4){0.f, 0.f, 0.f, 0.f};
    acc[1] = (f32x4){0.f, 0.f, 0.f, 0.f};
#pragma unroll
    for (int ks = 0; ks < 128; ks += 32) {
        bf16x8 a = *(const bf16x8*)&As[ln][ks + q * 8];
#pragma unroll
        for (int ct = 0; ct < 2; ct++) {
            bf16x8 bv = *(const bf16x8*)(Bt + (size_t)(w * 32 + ct * 16 + ln) * 128 + ks + q * 8);
            acc[ct] = __builtin_amdgcn_mfma_f32_16x16x32_bf16(a, bv, acc[ct], 0, 0, 0);
        }
    }
    float s1[4] = {0, 0, 0, 0}, s2[4] = {0, 0, 0, 0};
#pragma unroll
    for (int ct = 0; ct < 2; ct++)
#pragma unroll
        for (int r = 0; r < 4; r++) {
            float v = acc[ct][r] + bias[w * 32 + ct * 16 + ln];
            acc[ct][r] = v;
            s1[r] += v;
            s2[r] += v * v;
        }
#pragma unroll
    for (int off = 1; off < 16; off <<= 1)
#pragma unroll
        for (int r = 0; r < 4; r++) {
            s1[r] += __shfl_xor(s1[r], off, 64);
            s2[r] += __shfl_xor(s2[r], off, 64);
        }
    if (ln == 0)
#pragma unroll
        for (int r = 0; r < 4; r++) {
            pS[w][q * 4 + r] = s1[r];
            pQ[w][q * 4 + r] = s2[r];
        }
    __syncthreads();
#pragma unroll
    for (int r = 0; r < 4; r++) {
        int row = q * 4 + r;
        float S = 0.f, Q = 0.f;
#pragma unroll
        for (int ww = 0; ww < 8; ww++) {
            S += pS[ww][row];
            Q += pQ[ww][row];
        }
        float mu = S * (1.f / 256.f);
        float var = Q * (1.f / 256.f) - mu * mu;
        float rs = rsqrtf(var + 1e-5f);
#pragma unroll
        for (int ct = 0; ct < 2; ct++) {
            int col = w * 32 + ct * 16 + ln;
            float y = (acc[ct][r] - mu) * rs * mg[col] + mb[col];
            z1s[row][col] = f2bf(fmaxf(y, 0.f));
        }
    }
    __syncthreads();
}

// ---- out gemm (8 waves): v = A(16xKD)@B^T + bias (+h); h=v; LN128+lrelu ---
template <int KD, bool RESID>
__device__ __forceinline__ void out_stage8(const ushort* __restrict__ Abase, int astr,
                                           const ushort* __restrict__ Bt,
                                           const float* __restrict__ bias,
                                           const float* __restrict__ lg,
                                           const float* __restrict__ lb,
                                           float* __restrict__ hbuf,
                                           ushort* __restrict__ rout,
                                           float* __restrict__ rnbuf,
                                           int row0, int w, int q, int ln,
                                           float (*pS)[16], float (*pQ)[16]) {
    f32x4 acc = (f32x4){0.f, 0.f, 0.f, 0.f};
    int col = w * 16 + ln;
#pragma unroll
    for (int ks = 0; ks < KD; ks += 32) {
        bf16x8 a = *(const bf16x8*)(Abase + ln * astr + ks + q * 8);
        bf16x8 bv = *(const bf16x8*)(Bt + (size_t)col * KD + ks + q * 8);
        acc = __builtin_amdgcn_mfma_f32_16x16x32_bf16(a, bv, acc, 0, 0, 0);
    }
    float s1[4], s2[4];
#pragma unroll
    for (int r = 0; r < 4; r++) {
        int row = q * 4 + r;
        float v = acc[r] + bias[col];
        if (RESID) v += hbuf[(size_t)(row0 + row) * 128 + col];
        hbuf[(size_t)(row0 + row) * 128 + col] = v;
        acc[r] = v;
        s1[r] = v;
        s2[r] = v * v;
    }
#pragma unroll
    for (int off = 1; off < 16; off <<= 1)
#pragma unroll
        for (int r = 0; r < 4; r++) {
            s1[r] += __shfl_xor(s1[r], off, 64);
            s2[r] += __shfl_xor(s2[r], off, 64);
        }
    if (ln == 0)
#pragma unroll
        for (int r = 0; r < 4; r++) {
            pS[w][q * 4 + r] = s1[r];
            pQ[w][q * 4 + r] = s2[r];
        }
    __syncthreads();
    float yv[4];
    float t2[4];
#pragma unroll
    for (int r = 0; r < 4; r++) {
        int row = q * 4 + r;
        float S = 0.f, Q = 0.f;
#pragma unroll
        for (int ww = 0; ww < 8; ww++) {
            S += pS[ww][row];
            Q += pQ[ww][row];
        }
        float mu = S * (1.f / 128.f);
        float var = Q * (1.f / 128.f) - mu * mu;
        float rs = rsqrtf(var + 1e-5f);
        float y = (acc[r] - mu) * rs * lg[col] + lb[col];
        y = y > 0.f ? y : 0.01f * y;
        yv[r] = y;
        t2[r] = y * y;
    }
#pragma unroll
    for (int off = 1; off < 16; off <<= 1)
#pragma unroll
        for (int r = 0; r < 4; r++) t2[r] += __shfl_xor(t2[r], off, 64);
    __syncthreads();
    if (ln == 0)
#pragma unroll
        for (int r = 0; r < 4; r++) pS[w][q * 4 + r] = t2[r];
    __syncthreads();
#pragma unroll
    for (int r = 0; r < 4; r++) {
        int row = q * 4 + r;
        float T = 0.f;
#pragma unroll
        for (int ww = 0; ww < 8; ww++) T += pS[ww][row];
        if (w == 0 && ln == 0) rnbuf[row0 + row] = sqrtf(T);
        rout[(size_t)(row0 + row) * 128 + col] = f2bf(yv[r]);
    }
}

// ---------------- encoder: h = xb @ encW^T + b; LN0 + lrelu ----------------
__global__ __launch_bounds__(BT) void enc_kernel(const ushort* __restrict__ xb,
                                                 const ushort* __restrict__ encWt,
                                                 const float* __restrict__ encB,
                                                 const float* __restrict__ lg,
                                                 const float* __restrict__ lb,
                                                 float* __restrict__ h,
                                                 ushort* __restrict__ rbuf,
                                                 float* __restrict__ rn, int N) {
    __shared__ __align__(16) ushort As[16][136];
    __shared__ float pS[8][16], pQ[8][16];
    uint(*AsU)[68] = (uint(*)[68])As;
    int tid = threadIdx.x, w = tid >> 6, l = tid & 63;
    int q = l >> 4, ln = l & 15;
    int row0 = blockIdx.x * 16;
    for (int idx = tid; idx < 16 * 64; idx += BT) {
        int row = idx >> 6, cl = idx & 63;
        AsU[row][cl] = ((const uint*)xb)[(size_t)(row0 + row) * 64 + cl];
    }
    __syncthreads();
    out_stage8<128, false>(&As[0][0], 136, encWt, encB, lg, lb, h, rbuf, rn,
                           row0, w, q, ln, pS, pQ);
}

// ---------------- fused layer: 16-row tile, agg + gemm1 + gemm2 ------------
__global__ __launch_bounds__(BT) void layer_kernel(const ushort* __restrict__ rin,
                                                   ushort* __restrict__ rout,
                                                   const int* __restrict__ offs,
                                                   const int* __restrict__ esrc,
                                                   float* __restrict__ rn,
                                                   float* __restrict__ h,
                                                   const ushort* __restrict__ W1t,
                                                   const ushort* __restrict__ W2t,
                                                   const float* __restrict__ b1,
                                                   const float* __restrict__ mg,
                                                   const float* __restrict__ mb,
                                                   const float* __restrict__ b2,
                                                   const float* __restrict__ ng,
                                                   const float* __restrict__ nb,
                                                   const float* __restrict__ tptr,
                                                   const float* __restrict__ scptr,
                                                   int N) {
    __shared__ __align__(16) ushort As[16][136];
    __shared__ __align__(16) ushort z1s[16][264];
    __shared__ float pS[8][16], pQ[8][16];
    uint(*AsU)[68] = (uint(*)[68])As;
    int tid = threadIdx.x, w = tid >> 6, l = tid & 63;
    int q = l >> 4, ln = l & 15;
    int row0 = blockIdx.x * 16;
    float tv2 = (*tptr) * 1.4426950408889634f;  // fold log2(e) into temperature
    float sv = *scptr;
    agg_stage_v18(rin, offs, esrc, rn, tv2, sv, row0, w, l, AsU);
    __syncthreads();
    gemm1_stage8(As, W1t, b1, mg, mb, z1s, w, q, ln, pS, pQ);
    out_stage8<256, true>(&z1s[0][0], 264, W2t, b2, ng, nb, h, rout, rn,
                          row0, w, q, ln, pS, pQ);
}

// ---------------- pool: one block per graph, 4 waves over rows -------------
__global__ __launch_bounds__(256) void pool_kernel(const ushort* __restrict__ rf,
                                                   const int* __restrict__ gstart,
                                                   float* __restrict__ out) {
    __shared__ float pb0[4][64], pb1[4][64];
    int g = blockIdx.x;
    int w = threadIdx.x >> 6, l = threadIdx.x & 63;
    int s = gstart[g], e = gstart[g + 1];
    float a0 = 0.f, a1 = 0.f;
    for (int n = s + w; n < e; n += 4) {
        uint rv = ((const uint*)rf)[(size_t)n * 64 + l];
        a0 += bf2f((ushort)(rv & 0xffff));
        a1 += bf2f((ushort)(rv >> 16));
    }
    pb0[w][l] = a0;
    pb1[w][l] = a1;
    __syncthreads();
    if (threadIdx.x < 64) {
        float t0 = pb0[0][l] + pb0[1][l] + pb0[2][l] + pb0[3][l];
        float t1 = pb1[0][l] + pb1[1][l] + pb1[2][l] + pb1[3][l];
        float inv = 1.f / fmaxf((float)(e - s), 1.f);
        out[g * 128 + 2 * l] = t0 * inv;
        out[g * 128 + 2 * l + 1] = t1 * inv;
    }
}

// ---------------------------------------------------------------------------
extern "C" void kernel_launch(void* const* d_in, const int* in_sizes, int n_in,
                              void* d_out, int out_size, void* d_ws, size_t ws_size,
                              hipStream_t stream) {
    const float* x     = (const float*)d_in[0];
    const int*   ei    = (const int*)d_in[1];
    const int*   batch = (const int*)d_in[2];
    const float* encW  = (const float*)d_in[3];
    const float* encB  = (const float*)d_in[4];
    const float* ln_g  = (const float*)d_in[5];
    const float* ln_b  = (const float*)d_in[6];
    const float* tArr  = (const float*)d_in[7];
    const float* scArr = (const float*)d_in[8];
    const float* W1    = (const float*)d_in[9];
    const float* b1    = (const float*)d_in[10];
    const float* mg    = (const float*)d_in[11];
    const float* mb    = (const float*)d_in[12];
    const float* W2    = (const float*)d_in[13];
    const float* b2    = (const float*)d_in[14];
    const float* fn_g  = (const float*)d_in[15];
    const float* fn_b  = (const float*)d_in[16];
    float* out = (float*)d_out;

    const int N = in_sizes[0] / 128;  // 10000
    const int E = in_sizes[1] / 2;    // 160000
    const int L = in_sizes[7];        // 14
    const int G = 64;

    const int* src = ei;
    const int* dst = ei + E;

    char* p = (char*)d_ws;
    auto alloc = [&](size_t bytes) -> void* {
        void* qp = (void*)p;
        p += (bytes + 255) & ~(size_t)255;
        return qp;
    };
    int*    deg    = (int*)alloc((size_t)N * 4);
    int*    offs   = (int*)alloc((size_t)(N + 1) * 4);
    int*    cursor = (int*)alloc((size_t)N * 4);
    int*    esrc   = (int*)alloc((size_t)E * 4);
    int*    gstart = (int*)alloc((size_t)(G + 1) * 4);
    float*  h      = (float*)alloc((size_t)N * 128 * 4);
    ushort* r0     = (ushort*)alloc((size_t)N * 128 * 2);
    ushort* r1     = (ushort*)alloc((size_t)N * 128 * 2);
    float*  rn     = (float*)alloc((size_t)N * 4);
    ushort* xb     = (ushort*)alloc((size_t)N * 128 * 2);
    ushort* W1t    = (ushort*)alloc((size_t)L * 32768 * 2);
    ushort* W2t    = (ushort*)alloc((size_t)L * 32768 * 2);
    ushort* encWt  = (ushort*)alloc((size_t)16384 * 2);

    (void)hipMemsetAsync(deg, 0, (size_t)N * 4, stream);

    setup_kernel<<<(N * 128 + 255) / 256, 256, 0, stream>>>(x, xb, dst, deg, batch,
                                                            gstart, N * 128, N, E, G);
    scan_kernel<<<1, 1024, 0, stream>>>(deg, offs, cursor, N);
    scatter_kernel<<<(E + 255) / 256, 256, 0, stream>>>(src, dst, cursor, esrc, E);
    prep_kernel<<<dim3(8, 8, 2 * L + 1), 256, 0, stream>>>(W1, W2, encW, W1t, W2t,
                                                           encWt, L);

    const int TILES = N / 16;  // 625

    enc_kernel<<<TILES, BT, 0, stream>>>(xb, encWt, encB, ln_g, ln_b, h, r0, rn, N);

    for (int i = 0; i < L; i++) {
        const ushort* rin = (i & 1) ? r1 : r0;
        ushort* rout = (i & 1) ? r0 : r1;
        const float* ng = (i < L - 1) ? (ln_g + (size_t)(i + 1) * 128) : fn_g;
        const float* nb = (i < L - 1) ? (ln_b + (size_t)(i + 1) * 128) : fn_b;
        layer_kernel<<<TILES, BT, 0, stream>>>(rin, rout, offs, esrc, rn, h,
                                               W1t + ((size_t)i << 15),
                                               W2t + ((size_t)i << 15),
                                               b1 + (size_t)i * 256,
                                               mg + (size_t)i * 256,
                                               mb + (size_t)i * 256,
                                               b2 + (size_t)i * 128,
                                               ng, nb, tArr + i, scArr + i, N);
    }

    // last layer i=L-1 wrote rout = ((L-1)&1) ? r0 : r1
    const ushort* rf = ((L - 1) & 1) ? r0 : r1;
    pool_kernel<<<G, 256, 0, stream>>>(rf, gstart, out);
}

// Round 19
// 570.841 us; speedup vs baseline: 1.4280x; 1.0143x over previous
//
#include <hip/hip_runtime.h>
#include <cstdint>
#include <cstddef>

// ---------------------------------------------------------------------------
// DeeperGCN forward on MI355X. Round 19: round 18 (best, 579 us) + degree-
// sorted node remap: counting-sort nodes by DESCENDING degree into perm[];
// layer waves process perm[row0+2w{,+1}]. Kills (a) pair-max penalty (paired
// nodes have ~equal degree), (b) tile imbalance (tiles degree-uniform),
// (c) gives LPT makespan free (heavy tiles at low block idx). Gathers and
// rin layout untouched (round 16's locality mistake avoided); h/rout writes
// stay row-contiguous (256 B), just row-scattered.
// Layer: 512 thr / 8 waves, 2 nodes/wave, wave-preloaded indices + half-wave
// uint2 gathers (8 in flight), max-free softmax, exp2-folded, 16-row tiles.
// N=10000 nodes, E=160000 edges, H=128, L=14 layers, G=64 graphs.
// ---------------------------------------------------------------------------

#define BT 512  // 8 waves

typedef __attribute__((ext_vector_type(8))) short bf16x8;
typedef __attribute__((ext_vector_type(4))) float f32x4;

__device__ inline float bf2f(ushort u) {
    union { uint i; float f; } v;
    v.i = (uint)u << 16;
    return v.f;
}
__device__ inline ushort f2bf(float f) {
    union { float f; uint i; } v;
    v.f = f;
    return (ushort)((v.i + 0x7fffu + ((v.i >> 16) & 1u)) >> 16);
}
__device__ inline uint f2bf2(float a, float b) {
    return (uint)f2bf(a) | ((uint)f2bf(b) << 16);
}
__device__ inline float fast_exp2(float x) {
    return __builtin_amdgcn_exp2f(x);  // v_exp_f32: D = 2^S0
}

// ---------------- setup: xb convert + deg histogram + graph boundaries -----
__global__ void setup_kernel(const float* __restrict__ x, ushort* __restrict__ xb,
                             const int* __restrict__ dst, int* __restrict__ deg,
                             const int* __restrict__ batch, int* __restrict__ gstart,
                             int total, int N, int E, int G) {
    int idx = blockIdx.x * blockDim.x + threadIdx.x;
    if (idx >= total) return;
    xb[idx] = f2bf(x[idx]);
    if (idx < E) atomicAdd(&deg[dst[idx]], 1);
    if (idx < N) {
        int bb = batch[idx];
        if (idx == 0)
            for (int g = 0; g <= bb; g++) gstart[g] = 0;
        else {
            int pb = batch[idx - 1];
            for (int g = pb + 1; g <= bb; g++) gstart[g] = idx;
        }
        if (idx == N - 1)
            for (int g = bb + 1; g <= G; g++) gstart[g] = N;
    }
}

// single-workgroup exclusive scan of deg -> offs, cursor
__global__ __launch_bounds__(1024) void scan_kernel(const int* __restrict__ deg,
                                                    int* __restrict__ offs,
                                                    int* __restrict__ cursor, int N) {
    __shared__ int part[1024];
    int tid = threadIdx.x;
    int CH = (N + 1023) / 1024;
    int base = tid * CH;
    int s = 0;
    for (int i = 0; i < CH; i++) {
        int idx = base + i;
        if (idx < N) s += deg[idx];
    }
    part[tid] = s;
    __syncthreads();
    for (int off = 1; off < 1024; off <<= 1) {
        int v = (tid >= off) ? part[tid - off] : 0;
        __syncthreads();
        part[tid] += v;
        __syncthreads();
    }
    int run = (tid == 0) ? 0 : part[tid - 1];
    for (int i = 0; i < CH; i++) {
        int idx = base + i;
        if (idx < N) {
            offs[idx] = run;
            cursor[idx] = run;
            run += deg[idx];
        }
    }
    if (tid == 1023) offs[N] = part[1023];
}

__global__ void scatter_kernel(const int* __restrict__ src, const int* __restrict__ dst,
                               int* __restrict__ cursor, int* __restrict__ esrc, int E) {
    int e = blockIdx.x * blockDim.x + threadIdx.x;
    if (e < E) {
        int d = dst[e];
        int pos = atomicAdd(&cursor[d], 1);
        esrc[pos] = src[e];
    }
}

// ---- counting sort: perm[] = node ids by DESCENDING degree ----------------
__global__ __launch_bounds__(1024) void sort_kernel(const int* __restrict__ offs,
                                                    int* __restrict__ perm, int N) {
    __shared__ int hist[256];
    __shared__ int cur[256];
    int tid = threadIdx.x;
    if (tid < 256) hist[tid] = 0;
    __syncthreads();
    for (int n = tid; n < N; n += 1024) {
        int d = offs[n + 1] - offs[n];
        int key = 255 - min(d, 255);
        atomicAdd(&hist[key], 1);
    }
    __syncthreads();
    if (tid == 0) {
        int run = 0;
        for (int i = 0; i < 256; i++) {
            cur[i] = run;
            run += hist[i];
        }
    }
    __syncthreads();
    for (int n = tid; n < N; n += 1024) {
        int d = offs[n + 1] - offs[n];
        int key = 255 - min(d, 255);
        int pos = atomicAdd(&cur[key], 1);
        perm[pos] = n;
    }
}

// ---------------- weight prep: fp32 [R][C] -> bf16 [C][R], all matrices ----
__global__ __launch_bounds__(256) void prep_kernel(const float* __restrict__ W1,
                                                   const float* __restrict__ W2,
                                                   const float* __restrict__ encW,
                                                   ushort* __restrict__ W1t,
                                                   ushort* __restrict__ W2t,
                                                   ushort* __restrict__ encWt, int L) {
    __shared__ float tile[32][33];
    int z = blockIdx.z;
    const float* in;
    ushort* out;
    int R, C;
    if (z < L) {
        in = W1 + (size_t)z * 32768; out = W1t + (size_t)z * 32768; R = 128; C = 256;
    } else if (z < 2 * L) {
        int i = z - L;
        in = W2 + (size_t)i * 32768; out = W2t + (size_t)i * 32768; R = 256; C = 128;
    } else {
        in = encW; out = encWt; R = 128; C = 128;
    }
    int r0 = blockIdx.y * 32, c0 = blockIdx.x * 32;
    if (r0 >= R || c0 >= C) return;
    int tx = threadIdx.x & 31, ty = threadIdx.x >> 5;
    for (int i = ty; i < 32; i += 8) tile[i][tx] = in[(size_t)(r0 + i) * C + c0 + tx];
    __syncthreads();
    for (int i = ty; i < 32; i += 8)
        out[(size_t)(c0 + i) * R + r0 + tx] = f2bf(tile[tx][i]);
}

// ---- aggregation v19: 2 (perm-adjacent, equal-degree) nodes/wave ----------
__device__ __forceinline__ void agg_stage_v19(const ushort* __restrict__ rin,
                                              const int* __restrict__ offs,
                                              const int* __restrict__ esrc,
                                              const float* __restrict__ rnbuf,
                                              float tv2, float sv,
                                              int nd0, int nd1,
                                              int w, int l, uint (*AsU)[68]) {
    const uint2* rin2 = (const uint2*)rin;
    int half = l >> 5, li = l & 31;
    int eb[2], dg[2];
    eb[0] = offs[nd0]; dg[0] = offs[nd0 + 1] - eb[0];
    eb[1] = offs[nd1]; dg[1] = offs[nd1 + 1] - eb[1];

    // prefetch (independent of gather loop): own rows + rn for both nodes
    uint2 ru0 = rin2[(size_t)nd0 * 32 + li];
    uint2 ru1 = rin2[(size_t)nd1 * 32 + li];
    float rn0 = rnbuf[nd0], rn1 = rnbuf[nd1];

    float s[2][4] = {}, W[2][4] = {};
    int mxdeg = max(dg[0], dg[1]);

#pragma unroll 1
    for (int base = 0; base < mxdeg; base += 64) {
        int rem0 = min(dg[0] - base, 64);
        int rem1 = min(dg[1] - base, 64);
        int idx0 = (rem0 > 0 && l < rem0) ? esrc[eb[0] + base + l] : 0;
        int idx1 = (rem1 > 0 && l < rem1) ? esrc[eb[1] + base + l] : 0;
        int it = (max(rem0, rem1) + 7) >> 3;
#pragma unroll 1
        for (int i = 0; i < it; i++) {
            int j0 = i * 8 + half;
            uint2 rv[2][4];
            bool vl[2][4];
#pragma unroll
            for (int c = 0; c < 4; c++) {
                int j = j0 + 2 * c;
                vl[0][c] = j < rem0;
                vl[1][c] = j < rem1;
                int sn0 = __shfl(idx0, j, 64);
                int sn1 = __shfl(idx1, j, 64);
                if (vl[0][c]) rv[0][c] = rin2[(size_t)sn0 * 32 + li];
                if (vl[1][c]) rv[1][c] = rin2[(size_t)sn1 * 32 + li];
            }
#pragma unroll
            for (int k = 0; k < 2; k++)
#pragma unroll
                for (int c = 0; c < 4; c++) {
                    if (vl[k][c]) {
                        float f0 = bf2f((ushort)(rv[k][c].x & 0xffff));
                        float f1 = bf2f((ushort)(rv[k][c].x >> 16));
                        float f2 = bf2f((ushort)(rv[k][c].y & 0xffff));
                        float f3 = bf2f((ushort)(rv[k][c].y >> 16));
                        float g0 = fmaxf(f0, 0.f) + 1e-7f;
                        float g1 = fmaxf(f1, 0.f) + 1e-7f;
                        float g2 = fmaxf(f2, 0.f) + 1e-7f;
                        float g3 = fmaxf(f3, 0.f) + 1e-7f;
                        float p0 = fast_exp2(g0 * tv2);
                        float p1 = fast_exp2(g1 * tv2);
                        float p2 = fast_exp2(g2 * tv2);
                        float p3 = fast_exp2(g3 * tv2);
                        s[k][0] += p0; W[k][0] += g0 * p0;
                        s[k][1] += p1; W[k][1] += g1 * p1;
                        s[k][2] += p2; W[k][2] += g2 * p2;
                        s[k][3] += p3; W[k][3] += g3 * p3;
                    }
                }
        }
    }

    // merge halves (associative sums), then per-node epilogue
#pragma unroll
    for (int k = 0; k < 2; k++) {
#pragma unroll
        for (int f = 0; f < 4; f++) {
            s[k][f] += __shfl_xor(s[k][f], 32, 64);
            W[k][f] += __shfl_xor(W[k][f], 32, 64);
        }
        float agg[4], nsq = 0.f;
#pragma unroll
        for (int f = 0; f < 4; f++) {
            agg[f] = W[k][f] / (s[k][f] + 1e-16f);
            nsq += agg[f] * agg[f];
        }
#pragma unroll
        for (int off = 1; off < 32; off <<= 1) nsq += __shfl_xor(nsq, off, 64);
        float rnv = (k == 0) ? rn0 : rn1;
        uint2 ru = (k == 0) ? ru0 : ru1;
        float fac = rnv * sv / fmaxf(sqrtf(nsq), 1e-12f);
        if (half == 0) {
            uint2 o;
            o.x = f2bf2(bf2f((ushort)(ru.x & 0xffff)) + agg[0] * fac,
                        bf2f((ushort)(ru.x >> 16)) + agg[1] * fac);
            o.y = f2bf2(bf2f((ushort)(ru.y & 0xffff)) + agg[2] * fac,
                        bf2f((ushort)(ru.y >> 16)) + agg[3] * fac);
            *(uint2*)&AsU[2 * w + k][2 * li] = o;
        }
    }
}

// ---- gemm1 (8 waves): z1 = relu(LN256(A(16x128) @ W1^T + b1)) into LDS ----
__device__ __forceinline__ void gemm1_stage8(const ushort (*As)[136],
                                             const ushort* __restrict__ Bt,
                                             const float* __restrict__ bias,
                                             const float* __restrict__ mg,
                                             const float* __restrict__ mb,
                                             ushort (*z1s)[264],
                                             int w, int q, int ln,
                                             float (*pS)[16], float (*pQ)[16]) {
    f32x4 acc[2];
    acc[0] = (f32x4){0.f, 0.f, 0.f, 0.f};
    acc[1] = (f32x4){0.f, 0.f, 0.f, 0.f};
#pragma unroll
    for (int ks = 0; ks < 128; ks += 32) {
        bf16x8 a = *(const bf16x8*)&As[ln][ks + q * 8];
#pragma unroll
        for (int ct = 0; ct < 2; ct++) {
            bf16x8 bv = *(const bf16x8*)(Bt + (size_t)(w * 32 + ct * 16 + ln) * 128 + ks + q * 8);
            acc[ct] = __builtin_amdgcn_mfma_f32_16x16x32_bf16(a, bv, acc[ct], 0, 0, 0);
        }
    }
    float s1[4] = {0, 0, 0, 0}, s2[4] = {0, 0, 0, 0};
#pragma unroll
    for (int ct = 0; ct < 2; ct++)
#pragma unroll
        for (int r = 0; r < 4; r++) {
            float v = acc[ct][r] + bias[w * 32 + ct * 16 + ln];
            acc[ct][r] = v;
            s1[r] += v;
            s2[r] += v * v;
        }
#pragma unroll
    for (int off = 1; off < 16; off <<= 1)
#pragma unroll
        for (int r = 0; r < 4; r++) {
            s1[r] += __shfl_xor(s1[r], off, 64);
            s2[r] += __shfl_xor(s2[r], off, 64);
        }
    if (ln == 0)
#pragma unroll
        for (int r = 0; r < 4; r++) {
            pS[w][q * 4 + r] = s1[r];
            pQ[w][q * 4 + r] = s2[r];
        }
    __syncthreads();
#pragma unroll
    for (int r = 0; r < 4; r++) {
        int row = q * 4 + r;
        float S = 0.f, Q = 0.f;
#pragma unroll
        for (int ww = 0; ww < 8; ww++) {
            S += pS[ww][row];
            Q += pQ[ww][row];
        }
        float mu = S * (1.f / 256.f);
        float var = Q * (1.f / 256.f) - mu * mu;
        float rs = rsqrtf(var + 1e-5f);
#pragma unroll
        for (int ct = 0; ct < 2; ct++) {
            int col = w * 32 + ct * 16 + ln;
            float y = (acc[ct][r] - mu) * rs * mg[col] + mb[col];
            z1s[row][col] = f2bf(fmaxf(y, 0.f));
        }
    }
    __syncthreads();
}

// ---- out gemm (8 waves): rowmap[row] gives the global node row ------------
template <int KD, bool RESID>
__device__ __forceinline__ void out_stage8(const ushort* __restrict__ Abase, int astr,
                                           const ushort* __restrict__ Bt,
                                           const float* __restrict__ bias,
                                           const float* __restrict__ lg,
                                           const float* __restrict__ lb,
                                           float* __restrict__ hbuf,
                                           ushort* __restrict__ rout,
                                           float* __restrict__ rnbuf,
                                           const int* rowmap,
                                           int w, int q, int ln,
                                           float (*pS)[16], float (*pQ)[16]) {
    f32x4 acc = (f32x4){0.f, 0.f, 0.f, 0.f};
    int col = w * 16 + ln;
#pragma unroll
    for (int ks = 0; ks < KD; ks += 32) {
        bf16x8 a = *(const bf16x8*)(Abase + ln * astr + ks + q * 8);
        bf16x8 bv = *(const bf16x8*)(Bt + (size_t)col * KD + ks + q * 8);
        acc = __builtin_amdgcn_mfma_f32_16x16x32_bf16(a, bv, acc, 0, 0, 0);
    }
    float s1[4], s2[4];
#pragma unroll
    for (int r = 0; r < 4; r++) {
        int grow = rowmap[q * 4 + r];
        float v = acc[r] + bias[col];
        if (RESID) v += hbuf[(size_t)grow * 128 + col];
        hbuf[(size_t)grow * 128 + col] = v;
        acc[r] = v;
        s1[r] = v;
        s2[r] = v * v;
    }
#pragma unroll
    for (int off = 1; off < 16; off <<= 1)
#pragma unroll
        for (int r = 0; r < 4; r++) {
            s1[r] += __shfl_xor(s1[r], off, 64);
            s2[r] += __shfl_xor(s2[r], off, 64);
        }
    if (ln == 0)
#pragma unroll
        for (int r = 0; r < 4; r++) {
            pS[w][q * 4 + r] = s1[r];
            pQ[w][q * 4 + r] = s2[r];
        }
    __syncthreads();
    float yv[4];
    float t2[4];
#pragma unroll
    for (int r = 0; r < 4; r++) {
        int row = q * 4 + r;
        float S = 0.f, Q = 0.f;
#pragma unroll
        for (int ww = 0; ww < 8; ww++) {
            S += pS[ww][row];
            Q += pQ[ww][row];
        }
        float mu = S * (1.f / 128.f);
        float var = Q * (1.f / 128.f) - mu * mu;
        float rs = rsqrtf(var + 1e-5f);
        float y = (acc[r] - mu) * rs * lg[col] + lb[col];
        y = y > 0.f ? y : 0.01f * y;
        yv[r] = y;
        t2[r] = y * y;
    }
#pragma unroll
    for (int off = 1; off < 16; off <<= 1)
#pragma unroll
        for (int r = 0; r < 4; r++) t2[r] += __shfl_xor(t2[r], off, 64);
    __syncthreads();
    if (ln == 0)
#pragma unroll
        for (int r = 0; r < 4; r++) pS[w][q * 4 + r] = t2[r];
    __syncthreads();
#pragma unroll
    for (int r = 0; r < 4; r++) {
        int grow = rowmap[q * 4 + r];
        float T = 0.f;
#pragma unroll
        for (int ww = 0; ww < 8; ww++) T += pS[ww][q * 4 + r];
        if (w == 0 && ln == 0) rnbuf[grow] = sqrtf(T);
        rout[(size_t)grow * 128 + col] = f2bf(yv[r]);
    }
}

// ---------------- encoder: h = xb @ encW^T + b; LN0 + lrelu ----------------
__global__ __launch_bounds__(BT) void enc_kernel(const ushort* __restrict__ xb,
                                                 const ushort* __restrict__ encWt,
                                                 const float* __restrict__ encB,
                                                 const float* __restrict__ lg,
                                                 const float* __restrict__ lb,
                                                 float* __restrict__ h,
                                                 ushort* __restrict__ rbuf,
                                                 float* __restrict__ rn, int N) {
    __shared__ __align__(16) ushort As[16][136];
    __shared__ float pS[8][16], pQ[8][16];
    __shared__ int rowmap[16];
    uint(*AsU)[68] = (uint(*)[68])As;
    int tid = threadIdx.x, w = tid >> 6, l = tid & 63;
    int q = l >> 4, ln = l & 15;
    int row0 = blockIdx.x * 16;
    if (tid < 16) rowmap[tid] = row0 + tid;
    for (int idx = tid; idx < 16 * 64; idx += BT) {
        int row = idx >> 6, cl = idx & 63;
        AsU[row][cl] = ((const uint*)xb)[(size_t)(row0 + row) * 64 + cl];
    }
    __syncthreads();
    out_stage8<128, false>(&As[0][0], 136, encWt, encB, lg, lb, h, rbuf, rn,
                           rowmap, w, q, ln, pS, pQ);
}

// ---------------- fused layer: 16-row tile (perm-remapped) -----------------
__global__ __launch_bounds__(BT) void layer_kernel(const ushort* __restrict__ rin,
                                                   ushort* __restrict__ rout,
                                                   const int* __restrict__ offs,
                                                   const int* __restrict__ esrc,
                                                   const int* __restrict__ perm,
                                                   float* __restrict__ rn,
                                                   float* __restrict__ h,
                                                   const ushort* __restrict__ W1t,
                                                   const ushort* __restrict__ W2t,
                                                   const float* __restrict__ b1,
                                                   const float* __restrict__ mg,
                                                   const float* __restrict__ mb,
                                                   const float* __restrict__ b2,
                                                   const float* __restrict__ ng,
                                                   const float* __restrict__ nb,
                                                   const float* __restrict__ tptr,
                                                   const float* __restrict__ scptr,
                                                   int N) {
    __shared__ __align__(16) ushort As[16][136];
    __shared__ __align__(16) ushort z1s[16][264];
    __shared__ float pS[8][16], pQ[8][16];
    __shared__ int rowmap[16];
    uint(*AsU)[68] = (uint(*)[68])As;
    int tid = threadIdx.x, w = tid >> 6, l = tid & 63;
    int q = l >> 4, ln = l & 15;
    int row0 = blockIdx.x * 16;
    if (tid < 16) rowmap[tid] = perm[row0 + tid];
    __syncthreads();
    float tv2 = (*tptr) * 1.4426950408889634f;
    float sv = *scptr;
    agg_stage_v19(rin, offs, esrc, rn, tv2, sv,
                  rowmap[2 * w], rowmap[2 * w + 1], w, l, AsU);
    __syncthreads();
    gemm1_stage8(As, W1t, b1, mg, mb, z1s, w, q, ln, pS, pQ);
    out_stage8<256, true>(&z1s[0][0], 264, W2t, b2, ng, nb, h, rout, rn,
                          rowmap, w, q, ln, pS, pQ);
}

// ---------------- pool: one block per graph, 4 waves over rows -------------
__global__ __launch_bounds__(256) void pool_kernel(const ushort* __restrict__ rf,
                                                   const int* __restrict__ gstart,
                                                   float* __restrict__ out) {
    __shared__ float pb0[4][64], pb1[4][64];
    int g = blockIdx.x;
    int w = threadIdx.x >> 6, l = threadIdx.x & 63;
    int s = gstart[g], e = gstart[g + 1];
    float a0 = 0.f, a1 = 0.f;
    for (int n = s + w; n < e; n += 4) {
        uint rv = ((const uint*)rf)[(size_t)n * 64 + l];
        a0 += bf2f((ushort)(rv & 0xffff));
        a1 += bf2f((ushort)(rv >> 16));
    }
    pb0[w][l] = a0;
    pb1[w][l] = a1;
    __syncthreads();
    if (threadIdx.x < 64) {
        float t0 = pb0[0][l] + pb0[1][l] + pb0[2][l] + pb0[3][l];
        float t1 = pb1[0][l] + pb1[1][l] + pb1[2][l] + pb1[3][l];
        float inv = 1.f / fmaxf((float)(e - s), 1.f);
        out[g * 128 + 2 * l] = t0 * inv;
        out[g * 128 + 2 * l + 1] = t1 * inv;
    }
}

// ---------------------------------------------------------------------------
extern "C" void kernel_launch(void* const* d_in, const int* in_sizes, int n_in,
                              void* d_out, int out_size, void* d_ws, size_t ws_size,
                              hipStream_t stream) {
    const float* x     = (const float*)d_in[0];
    const int*   ei    = (const int*)d_in[1];
    const int*   batch = (const int*)d_in[2];
    const float* encW  = (const float*)d_in[3];
    const float* encB  = (const float*)d_in[4];
    const float* ln_g  = (const float*)d_in[5];
    const float* ln_b  = (const float*)d_in[6];
    const float* tArr  = (const float*)d_in[7];
    const float* scArr = (const float*)d_in[8];
    const float* W1    = (const float*)d_in[9];
    const float* b1    = (const float*)d_in[10];
    const float* mg    = (const float*)d_in[11];
    const float* mb    = (const float*)d_in[12];
    const float* W2    = (const float*)d_in[13];
    const float* b2    = (const float*)d_in[14];
    const float* fn_g  = (const float*)d_in[15];
    const float* fn_b  = (const float*)d_in[16];
    float* out = (float*)d_out;

    const int N = in_sizes[0] / 128;  // 10000
    const int E = in_sizes[1] / 2;    // 160000
    const int L = in_sizes[7];        // 14
    const int G = 64;

    const int* src = ei;
    const int* dst = ei + E;

    char* p = (char*)d_ws;
    auto alloc = [&](size_t bytes) -> void* {
        void* qp = (void*)p;
        p += (bytes + 255) & ~(size_t)255;
        return qp;
    };
    int*    deg    = (int*)alloc((size_t)N * 4);
    int*    offs   = (int*)alloc((size_t)(N + 1) * 4);
    int*    cursor = (int*)alloc((size_t)N * 4);
    int*    esrc   = (int*)alloc((size_t)E * 4);
    int*    gstart = (int*)alloc((size_t)(G + 1) * 4);
    int*    perm   = (int*)alloc((size_t)N * 4);
    float*  h      = (float*)alloc((size_t)N * 128 * 4);
    ushort* r0     = (ushort*)alloc((size_t)N * 128 * 2);
    ushort* r1     = (ushort*)alloc((size_t)N * 128 * 2);
    float*  rn     = (float*)alloc((size_t)N * 4);
    ushort* xb     = (ushort*)alloc((size_t)N * 128 * 2);
    ushort* W1t    = (ushort*)alloc((size_t)L * 32768 * 2);
    ushort* W2t    = (ushort*)alloc((size_t)L * 32768 * 2);
    ushort* encWt  = (ushort*)alloc((size_t)16384 * 2);

    (void)hipMemsetAsync(deg, 0, (size_t)N * 4, stream);

    setup_kernel<<<(N * 128 + 255) / 256, 256, 0, stream>>>(x, xb, dst, deg, batch,
                                                            gstart, N * 128, N, E, G);
    scan_kernel<<<1, 1024, 0, stream>>>(deg, offs, cursor, N);
    scatter_kernel<<<(E + 255) / 256, 256, 0, stream>>>(src, dst, cursor, esrc, E);
    sort_kernel<<<1, 1024, 0, stream>>>(offs, perm, N);
    prep_kernel<<<dim3(8, 8, 2 * L + 1), 256, 0, stream>>>(W1, W2, encW, W1t, W2t,
                                                           encWt, L);

    const int TILES = N / 16;  // 625

    enc_kernel<<<TILES, BT, 0, stream>>>(xb, encWt, encB, ln_g, ln_b, h, r0, rn, N);

    for (int i = 0; i < L; i++) {
        const ushort* rin = (i & 1) ? r1 : r0;
        ushort* rout = (i & 1) ? r0 : r1;
        const float* ng = (i < L - 1) ? (ln_g + (size_t)(i + 1) * 128) : fn_g;
        const float* nb = (i < L - 1) ? (ln_b + (size_t)(i + 1) * 128) : fn_b;
        layer_kernel<<<TILES, BT, 0, stream>>>(rin, rout, offs, esrc, perm, rn, h,
                                               W1t + ((size_t)i << 15),
                                               W2t + ((size_t)i << 15),
                                               b1 + (size_t)i * 256,
                                               mg + (size_t)i * 256,
                                               mb + (size_t)i * 256,
                                               b2 + (size_t)i * 128,
                                               ng, nb, tArr + i, scArr + i, N);
    }

    // last layer i=L-1 wrote rout = ((L-1)&1) ? r0 : r1
    const ushort* rf = ((L - 1) & 1) ? r0 : r1;
    pool_kernel<<<G, 256, 0, stream>>>(rf, gstart, out);
}

// Round 20
// 570.255 us; speedup vs baseline: 1.4294x; 1.0010x over previous
//
#include <hip/hip_runtime.h>
#include <cstdint>
#include <cstddef>

// ---------------------------------------------------------------------------
// DeeperGCN forward on MI355X. Round 20: round 19 (best, 571 us) + h residual
// stream stored in bf16 (5 MB -> 2.5 MB). Per-layer hot set 11 -> 8.5 MB ->
// better per-XCD L2 residency for the latency-critical r gathers (FETCH was
// 12.4 MB/layer = 5x the r table -> thrash-to-HBM). One bf16 rounding of h
// per layer; LN scale-invariance + 4x absmax headroom absorb it.
// Layer: 512 thr / 8 waves, degree-sorted node remap, 2 equal-degree
// nodes/wave, wave-preloaded indices + half-wave uint2 gathers, max-free
// softmax, exp2-folded, 16-row tiles, 625 blocks.
// N=10000 nodes, E=160000 edges, H=128, L=14 layers, G=64 graphs.
// ---------------------------------------------------------------------------

#define BT 512  // 8 waves

typedef __attribute__((ext_vector_type(8))) short bf16x8;
typedef __attribute__((ext_vector_type(4))) float f32x4;

__device__ inline float bf2f(ushort u) {
    union { uint i; float f; } v;
    v.i = (uint)u << 16;
    return v.f;
}
__device__ inline ushort f2bf(float f) {
    union { float f; uint i; } v;
    v.f = f;
    return (ushort)((v.i + 0x7fffu + ((v.i >> 16) & 1u)) >> 16);
}
__device__ inline uint f2bf2(float a, float b) {
    return (uint)f2bf(a) | ((uint)f2bf(b) << 16);
}
__device__ inline float fast_exp2(float x) {
    return __builtin_amdgcn_exp2f(x);  // v_exp_f32: D = 2^S0
}

// ---------------- setup: xb convert + deg histogram + graph boundaries -----
__global__ void setup_kernel(const float* __restrict__ x, ushort* __restrict__ xb,
                             const int* __restrict__ dst, int* __restrict__ deg,
                             const int* __restrict__ batch, int* __restrict__ gstart,
                             int total, int N, int E, int G) {
    int idx = blockIdx.x * blockDim.x + threadIdx.x;
    if (idx >= total) return;
    xb[idx] = f2bf(x[idx]);
    if (idx < E) atomicAdd(&deg[dst[idx]], 1);
    if (idx < N) {
        int bb = batch[idx];
        if (idx == 0)
            for (int g = 0; g <= bb; g++) gstart[g] = 0;
        else {
            int pb = batch[idx - 1];
            for (int g = pb + 1; g <= bb; g++) gstart[g] = idx;
        }
        if (idx == N - 1)
            for (int g = bb + 1; g <= G; g++) gstart[g] = N;
    }
}

// single-workgroup exclusive scan of deg -> offs, cursor
__global__ __launch_bounds__(1024) void scan_kernel(const int* __restrict__ deg,
                                                    int* __restrict__ offs,
                                                    int* __restrict__ cursor, int N) {
    __shared__ int part[1024];
    int tid = threadIdx.x;
    int CH = (N + 1023) / 1024;
    int base = tid * CH;
    int s = 0;
    for (int i = 0; i < CH; i++) {
        int idx = base + i;
        if (idx < N) s += deg[idx];
    }
    part[tid] = s;
    __syncthreads();
    for (int off = 1; off < 1024; off <<= 1) {
        int v = (tid >= off) ? part[tid - off] : 0;
        __syncthreads();
        part[tid] += v;
        __syncthreads();
    }
    int run = (tid == 0) ? 0 : part[tid - 1];
    for (int i = 0; i < CH; i++) {
        int idx = base + i;
        if (idx < N) {
            offs[idx] = run;
            cursor[idx] = run;
            run += deg[idx];
        }
    }
    if (tid == 1023) offs[N] = part[1023];
}

__global__ void scatter_kernel(const int* __restrict__ src, const int* __restrict__ dst,
                               int* __restrict__ cursor, int* __restrict__ esrc, int E) {
    int e = blockIdx.x * blockDim.x + threadIdx.x;
    if (e < E) {
        int d = dst[e];
        int pos = atomicAdd(&cursor[d], 1);
        esrc[pos] = src[e];
    }
}

// ---- counting sort: perm[] = node ids by DESCENDING degree ----------------
__global__ __launch_bounds__(1024) void sort_kernel(const int* __restrict__ offs,
                                                    int* __restrict__ perm, int N) {
    __shared__ int hist[256];
    __shared__ int cur[256];
    int tid = threadIdx.x;
    if (tid < 256) hist[tid] = 0;
    __syncthreads();
    for (int n = tid; n < N; n += 1024) {
        int d = offs[n + 1] - offs[n];
        int key = 255 - min(d, 255);
        atomicAdd(&hist[key], 1);
    }
    __syncthreads();
    if (tid == 0) {
        int run = 0;
        for (int i = 0; i < 256; i++) {
            cur[i] = run;
            run += hist[i];
        }
    }
    __syncthreads();
    for (int n = tid; n < N; n += 1024) {
        int d = offs[n + 1] - offs[n];
        int key = 255 - min(d, 255);
        int pos = atomicAdd(&cur[key], 1);
        perm[pos] = n;
    }
}

// ---------------- weight prep: fp32 [R][C] -> bf16 [C][R], all matrices ----
__global__ __launch_bounds__(256) void prep_kernel(const float* __restrict__ W1,
                                                   const float* __restrict__ W2,
                                                   const float* __restrict__ encW,
                                                   ushort* __restrict__ W1t,
                                                   ushort* __restrict__ W2t,
                                                   ushort* __restrict__ encWt, int L) {
    __shared__ float tile[32][33];
    int z = blockIdx.z;
    const float* in;
    ushort* out;
    int R, C;
    if (z < L) {
        in = W1 + (size_t)z * 32768; out = W1t + (size_t)z * 32768; R = 128; C = 256;
    } else if (z < 2 * L) {
        int i = z - L;
        in = W2 + (size_t)i * 32768; out = W2t + (size_t)i * 32768; R = 256; C = 128;
    } else {
        in = encW; out = encWt; R = 128; C = 128;
    }
    int r0 = blockIdx.y * 32, c0 = blockIdx.x * 32;
    if (r0 >= R || c0 >= C) return;
    int tx = threadIdx.x & 31, ty = threadIdx.x >> 5;
    for (int i = ty; i < 32; i += 8) tile[i][tx] = in[(size_t)(r0 + i) * C + c0 + tx];
    __syncthreads();
    for (int i = ty; i < 32; i += 8)
        out[(size_t)(c0 + i) * R + r0 + tx] = f2bf(tile[tx][i]);
}

// ---- aggregation: 2 (perm-adjacent, equal-degree) nodes/wave --------------
__device__ __forceinline__ void agg_stage(const ushort* __restrict__ rin,
                                          const int* __restrict__ offs,
                                          const int* __restrict__ esrc,
                                          const float* __restrict__ rnbuf,
                                          float tv2, float sv,
                                          int nd0, int nd1,
                                          int w, int l, uint (*AsU)[68]) {
    const uint2* rin2 = (const uint2*)rin;
    int half = l >> 5, li = l & 31;
    int eb[2], dg[2];
    eb[0] = offs[nd0]; dg[0] = offs[nd0 + 1] - eb[0];
    eb[1] = offs[nd1]; dg[1] = offs[nd1 + 1] - eb[1];

    // prefetch (independent of gather loop): own rows + rn for both nodes
    uint2 ru0 = rin2[(size_t)nd0 * 32 + li];
    uint2 ru1 = rin2[(size_t)nd1 * 32 + li];
    float rn0 = rnbuf[nd0], rn1 = rnbuf[nd1];

    float s[2][4] = {}, W[2][4] = {};
    int mxdeg = max(dg[0], dg[1]);

#pragma unroll 1
    for (int base = 0; base < mxdeg; base += 64) {
        int rem0 = min(dg[0] - base, 64);
        int rem1 = min(dg[1] - base, 64);
        int idx0 = (rem0 > 0 && l < rem0) ? esrc[eb[0] + base + l] : 0;
        int idx1 = (rem1 > 0 && l < rem1) ? esrc[eb[1] + base + l] : 0;
        int it = (max(rem0, rem1) + 7) >> 3;
#pragma unroll 1
        for (int i = 0; i < it; i++) {
            int j0 = i * 8 + half;
            uint2 rv[2][4];
            bool vl[2][4];
#pragma unroll
            for (int c = 0; c < 4; c++) {
                int j = j0 + 2 * c;
                vl[0][c] = j < rem0;
                vl[1][c] = j < rem1;
                int sn0 = __shfl(idx0, j, 64);
                int sn1 = __shfl(idx1, j, 64);
                if (vl[0][c]) rv[0][c] = rin2[(size_t)sn0 * 32 + li];
                if (vl[1][c]) rv[1][c] = rin2[(size_t)sn1 * 32 + li];
            }
#pragma unroll
            for (int k = 0; k < 2; k++)
#pragma unroll
                for (int c = 0; c < 4; c++) {
                    if (vl[k][c]) {
                        float f0 = bf2f((ushort)(rv[k][c].x & 0xffff));
                        float f1 = bf2f((ushort)(rv[k][c].x >> 16));
                        float f2 = bf2f((ushort)(rv[k][c].y & 0xffff));
                        float f3 = bf2f((ushort)(rv[k][c].y >> 16));
                        float g0 = fmaxf(f0, 0.f) + 1e-7f;
                        float g1 = fmaxf(f1, 0.f) + 1e-7f;
                        float g2 = fmaxf(f2, 0.f) + 1e-7f;
                        float g3 = fmaxf(f3, 0.f) + 1e-7f;
                        float p0 = fast_exp2(g0 * tv2);
                        float p1 = fast_exp2(g1 * tv2);
                        float p2 = fast_exp2(g2 * tv2);
                        float p3 = fast_exp2(g3 * tv2);
                        s[k][0] += p0; W[k][0] += g0 * p0;
                        s[k][1] += p1; W[k][1] += g1 * p1;
                        s[k][2] += p2; W[k][2] += g2 * p2;
                        s[k][3] += p3; W[k][3] += g3 * p3;
                    }
                }
        }
    }

    // merge halves (associative sums), then per-node epilogue
#pragma unroll
    for (int k = 0; k < 2; k++) {
#pragma unroll
        for (int f = 0; f < 4; f++) {
            s[k][f] += __shfl_xor(s[k][f], 32, 64);
            W[k][f] += __shfl_xor(W[k][f], 32, 64);
        }
        float agg[4], nsq = 0.f;
#pragma unroll
        for (int f = 0; f < 4; f++) {
            agg[f] = W[k][f] / (s[k][f] + 1e-16f);
            nsq += agg[f] * agg[f];
        }
#pragma unroll
        for (int off = 1; off < 32; off <<= 1) nsq += __shfl_xor(nsq, off, 64);
        float rnv = (k == 0) ? rn0 : rn1;
        uint2 ru = (k == 0) ? ru0 : ru1;
        float fac = rnv * sv / fmaxf(sqrtf(nsq), 1e-12f);
        if (half == 0) {
            uint2 o;
            o.x = f2bf2(bf2f((ushort)(ru.x & 0xffff)) + agg[0] * fac,
                        bf2f((ushort)(ru.x >> 16)) + agg[1] * fac);
            o.y = f2bf2(bf2f((ushort)(ru.y & 0xffff)) + agg[2] * fac,
                        bf2f((ushort)(ru.y >> 16)) + agg[3] * fac);
            *(uint2*)&AsU[2 * w + k][2 * li] = o;
        }
    }
}

// ---- gemm1 (8 waves): z1 = relu(LN256(A(16x128) @ W1^T + b1)) into LDS ----
__device__ __forceinline__ void gemm1_stage8(const ushort (*As)[136],
                                             const ushort* __restrict__ Bt,
                                             const float* __restrict__ bias,
                                             const float* __restrict__ mg,
                                             const float* __restrict__ mb,
                                             ushort (*z1s)[264],
                                             int w, int q, int ln,
                                             float (*pS)[16], float (*pQ)[16]) {
    f32x4 acc[2];
    acc[0] = (f32x4){0.f, 0.f, 0.f, 0.f};
    acc[1] = (f32x4){0.f, 0.f, 0.f, 0.f};
#pragma unroll
    for (int ks = 0; ks < 128; ks += 32) {
        bf16x8 a = *(const bf16x8*)&As[ln][ks + q * 8];
#pragma unroll
        for (int ct = 0; ct < 2; ct++) {
            bf16x8 bv = *(const bf16x8*)(Bt + (size_t)(w * 32 + ct * 16 + ln) * 128 + ks + q * 8);
            acc[ct] = __builtin_amdgcn_mfma_f32_16x16x32_bf16(a, bv, acc[ct], 0, 0, 0);
        }
    }
    float s1[4] = {0, 0, 0, 0}, s2[4] = {0, 0, 0, 0};
#pragma unroll
    for (int ct = 0; ct < 2; ct++)
#pragma unroll
        for (int r = 0; r < 4; r++) {
            float v = acc[ct][r] + bias[w * 32 + ct * 16 + ln];
            acc[ct][r] = v;
            s1[r] += v;
            s2[r] += v * v;
        }
#pragma unroll
    for (int off = 1; off < 16; off <<= 1)
#pragma unroll
        for (int r = 0; r < 4; r++) {
            s1[r] += __shfl_xor(s1[r], off, 64);
            s2[r] += __shfl_xor(s2[r], off, 64);
        }
    if (ln == 0)
#pragma unroll
        for (int r = 0; r < 4; r++) {
            pS[w][q * 4 + r] = s1[r];
            pQ[w][q * 4 + r] = s2[r];
        }
    __syncthreads();
#pragma unroll
    for (int r = 0; r < 4; r++) {
        int row = q * 4 + r;
        float S = 0.f, Q = 0.f;
#pragma unroll
        for (int ww = 0; ww < 8; ww++) {
            S += pS[ww][row];
            Q += pQ[ww][row];
        }
        float mu = S * (1.f / 256.f);
        float var = Q * (1.f / 256.f) - mu * mu;
        float rs = rsqrtf(var + 1e-5f);
#pragma unroll
        for (int ct = 0; ct < 2; ct++) {
            int col = w * 32 + ct * 16 + ln;
            float y = (acc[ct][r] - mu) * rs * mg[col] + mb[col];
            z1s[row][col] = f2bf(fmaxf(y, 0.f));
        }
    }
    __syncthreads();
}

// ---- out gemm (8 waves): h stored bf16; rowmap[row] = global node row -----
template <int KD, bool RESID>
__device__ __forceinline__ void out_stage8(const ushort* __restrict__ Abase, int astr,
                                           const ushort* __restrict__ Bt,
                                           const float* __restrict__ bias,
                                           const float* __restrict__ lg,
                                           const float* __restrict__ lb,
                                           ushort* __restrict__ hbuf,
                                           ushort* __restrict__ rout,
                                           float* __restrict__ rnbuf,
                                           const int* rowmap,
                                           int w, int q, int ln,
                                           float (*pS)[16], float (*pQ)[16]) {
    f32x4 acc = (f32x4){0.f, 0.f, 0.f, 0.f};
    int col = w * 16 + ln;
#pragma unroll
    for (int ks = 0; ks < KD; ks += 32) {
        bf16x8 a = *(const bf16x8*)(Abase + ln * astr + ks + q * 8);
        bf16x8 bv = *(const bf16x8*)(Bt + (size_t)col * KD + ks + q * 8);
        acc = __builtin_amdgcn_mfma_f32_16x16x32_bf16(a, bv, acc, 0, 0, 0);
    }
    float s1[4], s2[4];
#pragma unroll
    for (int r = 0; r < 4; r++) {
        int grow = rowmap[q * 4 + r];
        float v = acc[r] + bias[col];
        if (RESID) v += bf2f(hbuf[(size_t)grow * 128 + col]);
        hbuf[(size_t)grow * 128 + col] = f2bf(v);
        acc[r] = v;
        s1[r] = v;
        s2[r] = v * v;
    }
#pragma unroll
    for (int off = 1; off < 16; off <<= 1)
#pragma unroll
        for (int r = 0; r < 4; r++) {
            s1[r] += __shfl_xor(s1[r], off, 64);
            s2[r] += __shfl_xor(s2[r], off, 64);
        }
    if (ln == 0)
#pragma unroll
        for (int r = 0; r < 4; r++) {
            pS[w][q * 4 + r] = s1[r];
            pQ[w][q * 4 + r] = s2[r];
        }
    __syncthreads();
    float yv[4];
    float t2[4];
#pragma unroll
    for (int r = 0; r < 4; r++) {
        int row = q * 4 + r;
        float S = 0.f, Q = 0.f;
#pragma unroll
        for (int ww = 0; ww < 8; ww++) {
            S += pS[ww][row];
            Q += pQ[ww][row];
        }
        float mu = S * (1.f / 128.f);
        float var = Q * (1.f / 128.f) - mu * mu;
        float rs = rsqrtf(var + 1e-5f);
        float y = (acc[r] - mu) * rs * lg[col] + lb[col];
        y = y > 0.f ? y : 0.01f * y;
        yv[r] = y;
        t2[r] = y * y;
    }
#pragma unroll
    for (int off = 1; off < 16; off <<= 1)
#pragma unroll
        for (int r = 0; r < 4; r++) t2[r] += __shfl_xor(t2[r], off, 64);
    __syncthreads();
    if (ln == 0)
#pragma unroll
        for (int r = 0; r < 4; r++) pS[w][q * 4 + r] = t2[r];
    __syncthreads();
#pragma unroll
    for (int r = 0; r < 4; r++) {
        int grow = rowmap[q * 4 + r];
        float T = 0.f;
#pragma unroll
        for (int ww = 0; ww < 8; ww++) T += pS[ww][q * 4 + r];
        if (w == 0 && ln == 0) rnbuf[grow] = sqrtf(T);
        rout[(size_t)grow * 128 + col] = f2bf(yv[r]);
    }
}

// ---------------- encoder: h = xb @ encW^T + b; LN0 + lrelu ----------------
__global__ __launch_bounds__(BT) void enc_kernel(const ushort* __restrict__ xb,
                                                 const ushort* __restrict__ encWt,
                                                 const float* __restrict__ encB,
                                                 const float* __restrict__ lg,
                                                 const float* __restrict__ lb,
                                                 ushort* __restrict__ h,
                                                 ushort* __restrict__ rbuf,
                                                 float* __restrict__ rn, int N) {
    __shared__ __align__(16) ushort As[16][136];
    __shared__ float pS[8][16], pQ[8][16];
    __shared__ int rowmap[16];
    uint(*AsU)[68] = (uint(*)[68])As;
    int tid = threadIdx.x, w = tid >> 6, l = tid & 63;
    int q = l >> 4, ln = l & 15;
    int row0 = blockIdx.x * 16;
    if (tid < 16) rowmap[tid] = row0 + tid;
    for (int idx = tid; idx < 16 * 64; idx += BT) {
        int row = idx >> 6, cl = idx & 63;
        AsU[row][cl] = ((const uint*)xb)[(size_t)(row0 + row) * 64 + cl];
    }
    __syncthreads();
    out_stage8<128, false>(&As[0][0], 136, encWt, encB, lg, lb, h, rbuf, rn,
                           rowmap, w, q, ln, pS, pQ);
}

// ---------------- fused layer: 16-row tile (perm-remapped) -----------------
__global__ __launch_bounds__(BT) void layer_kernel(const ushort* __restrict__ rin,
                                                   ushort* __restrict__ rout,
                                                   const int* __restrict__ offs,
                                                   const int* __restrict__ esrc,
                                                   const int* __restrict__ perm,
                                                   float* __restrict__ rn,
                                                   ushort* __restrict__ h,
                                                   const ushort* __restrict__ W1t,
                                                   const ushort* __restrict__ W2t,
                                                   const float* __restrict__ b1,
                                                   const float* __restrict__ mg,
                                                   const float* __restrict__ mb,
                                                   const float* __restrict__ b2,
                                                   const float* __restrict__ ng,
                                                   const float* __restrict__ nb,
                                                   const float* __restrict__ tptr,
                                                   const float* __restrict__ scptr,
                                                   int N) {
    __shared__ __align__(16) ushort As[16][136];
    __shared__ __align__(16) ushort z1s[16][264];
    __shared__ float pS[8][16], pQ[8][16];
    __shared__ int rowmap[16];
    uint(*AsU)[68] = (uint(*)[68])As;
    int tid = threadIdx.x, w = tid >> 6, l = tid & 63;
    int q = l >> 4, ln = l & 15;
    int row0 = blockIdx.x * 16;
    if (tid < 16) rowmap[tid] = perm[row0 + tid];
    __syncthreads();
    float tv2 = (*tptr) * 1.4426950408889634f;
    float sv = *scptr;
    agg_stage(rin, offs, esrc, rn, tv2, sv,
              rowmap[2 * w], rowmap[2 * w + 1], w, l, AsU);
    __syncthreads();
    gemm1_stage8(As, W1t, b1, mg, mb, z1s, w, q, ln, pS, pQ);
    out_stage8<256, true>(&z1s[0][0], 264, W2t, b2, ng, nb, h, rout, rn,
                          rowmap, w, q, ln, pS, pQ);
}

// ---------------- pool: one block per graph, 4 waves over rows -------------
__global__ __launch_bounds__(256) void pool_kernel(const ushort* __restrict__ rf,
                                                   const int* __restrict__ gstart,
                                                   float* __restrict__ out) {
    __shared__ float pb0[4][64], pb1[4][64];
    int g = blockIdx.x;
    int w = threadIdx.x >> 6, l = threadIdx.x & 63;
    int s = gstart[g], e = gstart[g + 1];
    float a0 = 0.f, a1 = 0.f;
    for (int n = s + w; n < e; n += 4) {
        uint rv = ((const uint*)rf)[(size_t)n * 64 + l];
        a0 += bf2f((ushort)(rv & 0xffff));
        a1 += bf2f((ushort)(rv >> 16));
    }
    pb0[w][l] = a0;
    pb1[w][l] = a1;
    __syncthreads();
    if (threadIdx.x < 64) {
        float t0 = pb0[0][l] + pb0[1][l] + pb0[2][l] + pb0[3][l];
        float t1 = pb1[0][l] + pb1[1][l] + pb1[2][l] + pb1[3][l];
        float inv = 1.f / fmaxf((float)(e - s), 1.f);
        out[g * 128 + 2 * l] = t0 * inv;
        out[g * 128 + 2 * l + 1] = t1 * inv;
    }
}

// ---------------------------------------------------------------------------
extern "C" void kernel_launch(void* const* d_in, const int* in_sizes, int n_in,
                              void* d_out, int out_size, void* d_ws, size_t ws_size,
                              hipStream_t stream) {
    const float* x     = (const float*)d_in[0];
    const int*   ei    = (const int*)d_in[1];
    const int*   batch = (const int*)d_in[2];
    const float* encW  = (const float*)d_in[3];
    const float* encB  = (const float*)d_in[4];
    const float* ln_g  = (const float*)d_in[5];
    const float* ln_b  = (const float*)d_in[6];
    const float* tArr  = (const float*)d_in[7];
    const float* scArr = (const float*)d_in[8];
    const float* W1    = (const float*)d_in[9];
    const float* b1    = (const float*)d_in[10];
    const float* mg    = (const float*)d_in[11];
    const float* mb    = (const float*)d_in[12];
    const float* W2    = (const float*)d_in[13];
    const float* b2    = (const float*)d_in[14];
    const float* fn_g  = (const float*)d_in[15];
    const float* fn_b  = (const float*)d_in[16];
    float* out = (float*)d_out;

    const int N = in_sizes[0] / 128;  // 10000
    const int E = in_sizes[1] / 2;    // 160000
    const int L = in_sizes[7];        // 14
    const int G = 64;

    const int* src = ei;
    const int* dst = ei + E;

    char* p = (char*)d_ws;
    auto alloc = [&](size_t bytes) -> void* {
        void* qp = (void*)p;
        p += (bytes + 255) & ~(size_t)255;
        return qp;
    };
    int*    deg    = (int*)alloc((size_t)N * 4);
    int*    offs   = (int*)alloc((size_t)(N + 1) * 4);
    int*    cursor = (int*)alloc((size_t)N * 4);
    int*    esrc   = (int*)alloc((size_t)E * 4);
    int*    gstart = (int*)alloc((size_t)(G + 1) * 4);
    int*    perm   = (int*)alloc((size_t)N * 4);
    ushort* h      = (ushort*)alloc((size_t)N * 128 * 2);
    ushort* r0     = (ushort*)alloc((size_t)N * 128 * 2);
    ushort* r1     = (ushort*)alloc((size_t)N * 128 * 2);
    float*  rn     = (float*)alloc((size_t)N * 4);
    ushort* xb     = (ushort*)alloc((size_t)N * 128 * 2);
    ushort* W1t    = (ushort*)alloc((size_t)L * 32768 * 2);
    ushort* W2t    = (ushort*)alloc((size_t)L * 32768 * 2);
    ushort* encWt  = (ushort*)alloc((size_t)16384 * 2);

    (void)hipMemsetAsync(deg, 0, (size_t)N * 4, stream);

    setup_kernel<<<(N * 128 + 255) / 256, 256, 0, stream>>>(x, xb, dst, deg, batch,
                                                            gstart, N * 128, N, E, G);
    scan_kernel<<<1, 1024, 0, stream>>>(deg, offs, cursor, N);
    scatter_kernel<<<(E + 255) / 256, 256, 0, stream>>>(src, dst, cursor, esrc, E);
    sort_kernel<<<1, 1024, 0, stream>>>(offs, perm, N);
    prep_kernel<<<dim3(8, 8, 2 * L + 1), 256, 0, stream>>>(W1, W2, encW, W1t, W2t,
                                                           encWt, L);

    const int TILES = N / 16;  // 625

    enc_kernel<<<TILES, BT, 0, stream>>>(xb, encWt, encB, ln_g, ln_b, h, r0, rn, N);

    for (int i = 0; i < L; i++) {
        const ushort* rin = (i & 1) ? r1 : r0;
        ushort* rout = (i & 1) ? r0 : r1;
        const float* ng = (i < L - 1) ? (ln_g + (size_t)(i + 1) * 128) : fn_g;
        const float* nb = (i < L - 1) ? (ln_b + (size_t)(i + 1) * 128) : fn_b;
        layer_kernel<<<TILES, BT, 0, stream>>>(rin, rout, offs, esrc, perm, rn, h,
                                               W1t + ((size_t)i << 15),
                                               W2t + ((size_t)i << 15),
                                               b1 + (size_t)i * 256,
                                               mg + (size_t)i * 256,
                                               mb + (size_t)i * 256,
                                               b2 + (size_t)i * 128,
                                               ng, nb, tArr + i, scArr + i, N);
    }

    // last layer i=L-1 wrote rout = ((L-1)&1) ? r0 : r1
    const ushort* rf = ((L - 1) & 1) ? r0 : r1;
    pool_kernel<<<G, 256, 0, stream>>>(rf, gstart, out);
}